// Round 5
// baseline (841.886 us; speedup 1.0000x reference)
//
#include <hip/hip_runtime.h>

#define NN 20000
#define NE 40000
#define NGR 1000
#define WT_STRIDE 8256   // 8192 regular K + 64 bias-K columns
#define KH 2             // K-split factor for k_msg

typedef unsigned short u16;
typedef u16 u16x8 __attribute__((ext_vector_type(8)));
typedef __bf16 bf16x8 __attribute__((ext_vector_type(8)));
typedef float f32x4 __attribute__((ext_vector_type(4)));

union U8 { u16x8 u; bf16x8 b; };

__device__ __forceinline__ u16 f2bf(float f) {
    union { float f; unsigned u; } v; v.f = f;
    unsigned r = v.u + 0x7FFF + ((v.u >> 16) & 1);   // RNE
    return (u16)(r >> 16);
}
__device__ __forceinline__ float bf2f(u16 h) {
    union { unsigned u; float f; } v; v.u = ((unsigned)h) << 16;
    return v.f;
}
__device__ __forceinline__ float sigmoidf(float x) { return 1.f / (1.f + __expf(-x)); }

// ============ fused one-time preamble, grid-stride, 1152 blocks ============
// [0,64) transposes | [64,320) lin0 | [320,832) edge_mlp | [832,960) Wt gen
// [960,1024) cnt | [1024,1088) ranges | [1088,1152) zero hl/cl/qstar
__global__ __launch_bounds__(256) void k_pre(
    const float* __restrict__ x, const float* __restrict__ ea,
    const int* __restrict__ ei, const int* __restrict__ batch,
    const float* __restrict__ W0, const float* __restrict__ b0,
    const float* __restrict__ We1, const float* __restrict__ be1,
    const float* __restrict__ We2, const float* __restrict__ be2,
    const float* __restrict__ W_ih, const float* __restrict__ W_hh,
    const float* __restrict__ W_ihl, const float* __restrict__ W_hhl,
    const float* __restrict__ W1,
    float* __restrict__ h, u16* __restrict__ outb, u16* __restrict__ h1,
    u16* __restrict__ Wt, int* __restrict__ cnt,
    int* __restrict__ gstart, int* __restrict__ gend,
    float* __restrict__ WTih, float* __restrict__ WThh,
    float* __restrict__ WTihl, float* __restrict__ WThhl, float* __restrict__ WT1,
    float* __restrict__ hl, float* __restrict__ cl, float* __restrict__ qstar)
{
    const int b = blockIdx.x;
    const int t = threadIdx.x;

    if (b < 64) {                                    // weight transposes (81920 el)
        for (int idx = b * 256 + t; idx < 81920; idx += 64 * 256) {
            int i = idx;
            if (i < 12288) { WTih[i] = W_ih[(i % 192) * 64 + i / 192]; continue; }
            i -= 12288;
            if (i < 12288) { WThh[i] = W_hh[(i % 192) * 64 + i / 192]; continue; }
            i -= 12288;
            if (i < 32768) { WTihl[i] = W_ihl[(i % 256) * 128 + i / 256]; continue; }
            i -= 32768;
            if (i < 16384) { WThhl[i] = W_hhl[(i % 256) * 64 + i / 256]; continue; }
            i -= 16384;
            WT1[i] = W1[(i % 64) * 128 + i / 64];
        }
        return;
    }
    if (b < 320) {                                   // lin0: 1024 waves, grid-stride
        int wv = (b - 64) * 4 + (t >> 6);
        int lane = t & 63;
        float w0r[32];
#pragma unroll
        for (int f = 0; f < 32; ++f) w0r[f] = W0[lane * 32 + f];
        float b0v = b0[lane];
        for (int n = wv; n < NN; n += 1024) {
            float xv = (lane < 32) ? x[n * 32 + lane] : 0.f;
            float acc = b0v;
#pragma unroll
            for (int f = 0; f < 32; ++f) acc += __shfl(xv, f, 64) * w0r[f];
            float rv = fmaxf(acc, 0.f);
            h[n * 64 + lane] = rv;
            outb[n * 64 + lane] = f2bf(rv);
        }
        return;
    }
    if (b < 832) {                                   // edge MLP over NE*128
        for (int idx = (b - 320) * 256 + t; idx < NE * 128; idx += 512 * 256) {
            int e = idx >> 7, k = idx & 127;
            float acc = be1[k];
#pragma unroll
            for (int j = 0; j < 5; ++j)
                acc += ea[e * 5 + j] * We1[k * 5 + j];
            h1[idx] = f2bf(fmaxf(acc, 0.f));
        }
        return;
    }
    if (b < 960) {                                   // Wt gen over 64*8256
        for (int idx = (b - 832) * 256 + t; idx < 64 * WT_STRIDE; idx += 128 * 256) {
            int o = idx / WT_STRIDE, c = idx % WT_STRIDE;
            float v = (c < 8192) ? We2[((c >> 7) * 64 + o) * 128 + (c & 127)]
                                 : be2[(c - 8192) * 64 + o];
            Wt[idx] = f2bf(v);
        }
        return;
    }
    if (b < 1024) {                                  // degree count (int)
        for (int e = (b - 960) * 256 + t; e < NE; e += 64 * 256)
            atomicAdd(&cnt[ei[NE + e]], 1);
        return;
    }
    if (b < 1088) {                                  // graph ranges (batch sorted)
        for (int idx = (b - 1024) * 256 + t; idx < NN; idx += 64 * 256) {
            int bg = batch[idx];
            if (idx == 0 || batch[idx - 1] != bg) gstart[bg] = idx;
            if (idx == NN - 1 || batch[idx + 1] != bg) gend[bg] = idx + 1;
        }
        return;
    }
    {                                                // zero hl/cl/qstar (256000 f)
        for (int idx = (b - 1088) * 256 + t; idx < 256000; idx += 64 * 256) {
            if (idx < 64000) hl[idx] = 0.f;
            else if (idx < 128000) cl[idx - 64000] = 0.f;
            else qstar[idx - 128000] = 0.f;
        }
    }
}

// ---------------- exclusive prefix over cnt -> rowptr[NN+1], one block ----------
__global__ __launch_bounds__(1024) void k_scan(const int* __restrict__ cnt,
                                               int* __restrict__ rowptr)
{
    __shared__ int ps[1024];
    int t = threadIdx.x;
    int base = t * 20;
    int loc[20];
    int s = 0;
#pragma unroll
    for (int i = 0; i < 20; ++i) {
        int idx = base + i;
        loc[i] = s;
        s += (idx < NN) ? cnt[idx] : 0;
    }
    ps[t] = s;
    __syncthreads();
    for (int off = 1; off < 1024; off <<= 1) {
        int v = (t >= off) ? ps[t - off] : 0;
        __syncthreads();
        ps[t] += v;
        __syncthreads();
    }
    int ex = (t > 0) ? ps[t - 1] : 0;
#pragma unroll
    for (int i = 0; i < 20; ++i) {
        int idx = base + i;
        if (idx < NN) rowptr[idx] = ex + loc[i];
    }
    if (t == 1023) rowptr[NN] = ps[1023];
}

// ---------------- scatter edge ids into CSR ----------------
__global__ __launch_bounds__(256) void k_scatter(const int* __restrict__ ei,
    const int* __restrict__ rowptr, int* __restrict__ cur, int* __restrict__ eids)
{
    for (int e = blockIdx.x * 256 + threadIdx.x; e < NE; e += gridDim.x * 256) {
        int d = ei[NE + e];
        int pos = atomicAdd(&cur[d], 1);
        eids[rowptr[d] + pos] = e;
    }
}

// ---------------- message GEMM: barrier-free K-loop, no atomics -----------------
// pbuf[e][kh][o] = sum_{ch in kh slice} sv[e,ch]*(h1[e,:] . Wt[o,ch-block])
//                  (+ bias block on last kh).  B-frags direct from global (L2).
__global__ __launch_bounds__(128) void k_msg(
    const u16* __restrict__ outb, const u16* __restrict__ h1,
    const u16* __restrict__ Wt, const int* __restrict__ ei,
    float* __restrict__ pbuf)
{
    __shared__ __align__(16) u16 sh[128 * 72];   // sv rows (out[src]) bf16
    const int t = threadIdx.x;
    const int eb0 = blockIdx.x * 128;
    const int kh = blockIdx.y;                   // 0..KH-1

#pragma unroll
    for (int r = 0; r < 8; ++r) {                // gather out[src]: 128 rows
        int cid = t + 128 * r;
        int row = cid >> 3, c8 = cid & 7;
        int e = eb0 + row;
        u16x8 v = {};
        if (e < NE) { int s = ei[e]; v = *(const u16x8*)(outb + (size_t)s * 64 + c8 * 8); }
        *(u16x8*)&sh[row * 72 + c8 * 8] = v;
    }

    const int lane = t & 63, w = t >> 6, r16 = lane & 15, q = lane >> 4;
    const int w64 = w * 64;

    // static A-fragments: h1 rows, k = s4*32 + q*8 + j
    u16x8 h1r[4][4];
#pragma unroll
    for (int sub = 0; sub < 4; ++sub) {
        int e = eb0 + w64 + sub * 16 + r16;
        if (e >= NE) e = NE - 1;                 // contribution zeroed via sv=0
        const u16* hp = h1 + (size_t)e * 128 + q * 8;
#pragma unroll
        for (int s4 = 0; s4 < 4; ++s4)
            h1r[sub][s4] = *(const u16x8*)(hp + s4 * 32);
    }

    f32x4 acc[4][4];
    const f32x4 z4 = {0.f, 0.f, 0.f, 0.f};
#pragma unroll
    for (int sub = 0; sub < 4; ++sub)
#pragma unroll
        for (int nt = 0; nt < 4; ++nt) acc[sub][nt] = z4;
    __syncthreads();                             // the ONLY barrier

#pragma unroll 1
    for (int cc = 0; cc < 32; ++cc) {
        const int ch = kh * 32 + cc;
        const u16* wp = Wt + ch * 128 + q * 8;

        f32x4 P[4][4];
#pragma unroll
        for (int sub = 0; sub < 4; ++sub)
#pragma unroll
            for (int nt = 0; nt < 4; ++nt) P[sub][nt] = z4;

#pragma unroll
        for (int s4 = 0; s4 < 4; ++s4) {
            U8 bv[4];
#pragma unroll
            for (int nt = 0; nt < 4; ++nt)
                bv[nt].u = *(const u16x8*)(wp + (size_t)(nt * 16 + r16) * WT_STRIDE + s4 * 32);
#pragma unroll
            for (int sub = 0; sub < 4; ++sub) {
                U8 a; a.u = h1r[sub][s4];
#pragma unroll
                for (int nt = 0; nt < 4; ++nt)
                    P[sub][nt] = __builtin_amdgcn_mfma_f32_16x16x32_bf16(
                        a.b, bv[nt].b, P[sub][nt], 0, 0, 0);
            }
        }
        // scale by sv (row m = w64 + sub*16 + q*4 + r) and accumulate
#pragma unroll
        for (int sub = 0; sub < 4; ++sub) {
            int mb = w64 + sub * 16 + q * 4;
            float s0 = bf2f(sh[(mb + 0) * 72 + ch]);
            float s1 = bf2f(sh[(mb + 1) * 72 + ch]);
            float s2 = bf2f(sh[(mb + 2) * 72 + ch]);
            float s3 = bf2f(sh[(mb + 3) * 72 + ch]);
#pragma unroll
            for (int nt = 0; nt < 4; ++nt) {
                acc[sub][nt][0] += s0 * P[sub][nt][0];
                acc[sub][nt][1] += s1 * P[sub][nt][1];
                acc[sub][nt][2] += s2 * P[sub][nt][2];
                acc[sub][nt][3] += s3 * P[sub][nt][3];
            }
        }
    }

    if (kh == KH - 1) {   // bias block: A = out[src], B = Wt cols 8192..8255
        U8 bvb[2][4];
#pragma unroll
        for (int sb = 0; sb < 2; ++sb)
#pragma unroll
            for (int nt = 0; nt < 4; ++nt) {
                int o = nt * 16 + r16;
                bvb[sb][nt].u = *(const u16x8*)(Wt + (size_t)o * WT_STRIDE + 8192 + (sb * 4 + q) * 8);
            }
#pragma unroll
        for (int sub = 0; sub < 4; ++sub) {
            int m = w64 + sub * 16 + r16;
#pragma unroll
            for (int sb = 0; sb < 2; ++sb) {
                U8 a; a.u = *(const u16x8*)&sh[m * 72 + sb * 32 + q * 8];
#pragma unroll
                for (int nt = 0; nt < 4; ++nt)
                    acc[sub][nt] = __builtin_amdgcn_mfma_f32_16x16x32_bf16(
                        a.b, bvb[sb][nt].b, acc[sub][nt], 0, 0, 0);
            }
        }
    }

    // plain coalesced stores: pbuf[e][kh][o]
#pragma unroll
    for (int sub = 0; sub < 4; ++sub) {
#pragma unroll
        for (int r = 0; r < 4; ++r) {
            int e = eb0 + w64 + sub * 16 + q * 4 + r;
            if (e >= NE) continue;
            float* pp = pbuf + (size_t)e * (KH * 64) + kh * 64 + r16;
#pragma unroll
            for (int nt = 0; nt < 4; ++nt)
                pp[nt * 16] = acc[sub][nt][r];
        }
    }
}

// -------- GRU cell: CSR aggregation + deg-norm + gates, 8 nodes/wave ------------
__global__ __launch_bounds__(256) void k_gru(float* __restrict__ h, u16* __restrict__ outb,
    const float* __restrict__ pbuf, const int* __restrict__ rowptr,
    const int* __restrict__ eids, const float* __restrict__ b_conv,
    const float* __restrict__ WTih, const float* __restrict__ WThh,
    const float* __restrict__ b_ih, const float* __restrict__ b_hh)
{
    int wid = (blockIdx.x * blockDim.x + threadIdx.x) >> 6;
    int lane = threadIdx.x & 63;
    int n0 = wid * 8;
    if (n0 >= NN) return;
    float bcv = b_conv[lane];
    float m[8], hv[8];
#pragma unroll
    for (int p = 0; p < 8; ++p) {
        int n = n0 + p;
        int rs = rowptr[n], re = rowptr[n + 1];
        float v = 0.f;
        for (int j = rs; j < re; ++j) {
            const float* pb = pbuf + (size_t)eids[j] * (KH * 64);
            v += pb[lane] + pb[64 + lane];
        }
        float invd = 1.f / fmaxf((float)(re - rs), 1.f);
        m[p] = fmaxf(v * invd + bcv, 0.f);
        hv[p] = h[n * 64 + lane];
    }
    float air[8] = {}, aiz[8] = {}, ain[8] = {};
    float ahr[8] = {}, ahz[8] = {}, ahn[8] = {};
#pragma unroll 4
    for (int i = 0; i < 64; ++i) {
        const float* wi = WTih + i * 192;
        const float* wh = WThh + i * 192;
        float wir = wi[lane], wiz = wi[64 + lane], win = wi[128 + lane];
        float whr = wh[lane], whz = wh[64 + lane], whn = wh[128 + lane];
#pragma unroll
        for (int p = 0; p < 8; ++p) {
            float mi = __shfl(m[p], i, 64);
            float hi = __shfl(hv[p], i, 64);
            air[p] += mi * wir; aiz[p] += mi * wiz; ain[p] += mi * win;
            ahr[p] += hi * whr; ahz[p] += hi * whz; ahn[p] += hi * whn;
        }
    }
    float bir = b_ih[lane], biz = b_ih[64 + lane], bin = b_ih[128 + lane];
    float bhr = b_hh[lane], bhz = b_hh[64 + lane], bhn = b_hh[128 + lane];
#pragma unroll
    for (int p = 0; p < 8; ++p) {
        float r = sigmoidf(air[p] + bir + ahr[p] + bhr);
        float z = sigmoidf(aiz[p] + biz + ahz[p] + bhz);
        float nng = tanhf(ain[p] + bin + r * (ahn[p] + bhn));
        float hnew = (1.f - z) * nng + z * hv[p];
        h[(n0 + p) * 64 + lane] = hnew;
        outb[(n0 + p) * 64 + lane] = f2bf(hnew);
    }
}

// ---------------- Set2Set LSTM cell: 8 graphs/wave ------------------------------
__global__ __launch_bounds__(256) void k_lstm(float* __restrict__ hl, float* __restrict__ cl,
    const float* __restrict__ qstar,
    const float* __restrict__ WTihl, const float* __restrict__ WThhl,
    const float* __restrict__ b_ihl, const float* __restrict__ b_hhl)
{
    int wid = (blockIdx.x * blockDim.x + threadIdx.x) >> 6;
    int lane = threadIdx.x & 63;
    if (wid >= NGR / 8) return;
    int g0 = wid * 8;
    float q0[8], q1[8], hv[8];
    float gi[8] = {}, gf[8] = {}, gg[8] = {}, go[8] = {};
#pragma unroll
    for (int p = 0; p < 8; ++p) {
        q0[p] = qstar[(g0 + p) * 128 + lane];
        q1[p] = qstar[(g0 + p) * 128 + 64 + lane];
        hv[p] = hl[(g0 + p) * 64 + lane];
    }
#pragma unroll 2
    for (int j = 0; j < 64; ++j) {
        const float* wv = WTihl + j * 256;
        float wi = wv[lane], wf = wv[64 + lane], wg = wv[128 + lane], wo = wv[192 + lane];
#pragma unroll
        for (int p = 0; p < 8; ++p) {
            float a = __shfl(q0[p], j, 64);
            gi[p] += a * wi; gf[p] += a * wf; gg[p] += a * wg; go[p] += a * wo;
        }
    }
#pragma unroll 2
    for (int j = 0; j < 64; ++j) {
        const float* wv = WTihl + (64 + j) * 256;
        float wi = wv[lane], wf = wv[64 + lane], wg = wv[128 + lane], wo = wv[192 + lane];
#pragma unroll
        for (int p = 0; p < 8; ++p) {
            float a = __shfl(q1[p], j, 64);
            gi[p] += a * wi; gf[p] += a * wf; gg[p] += a * wg; go[p] += a * wo;
        }
    }
#pragma unroll 2
    for (int j = 0; j < 64; ++j) {
        const float* wv = WThhl + j * 256;
        float wi = wv[lane], wf = wv[64 + lane], wg = wv[128 + lane], wo = wv[192 + lane];
#pragma unroll
        for (int p = 0; p < 8; ++p) {
            float a = __shfl(hv[p], j, 64);
            gi[p] += a * wi; gf[p] += a * wf; gg[p] += a * wg; go[p] += a * wo;
        }
    }
    float bi = b_ihl[lane] + b_hhl[lane];
    float bf = b_ihl[64 + lane] + b_hhl[64 + lane];
    float bg = b_ihl[128 + lane] + b_hhl[128 + lane];
    float bo = b_ihl[192 + lane] + b_hhl[192 + lane];
#pragma unroll
    for (int p = 0; p < 8; ++p) {
        float cv = cl[(g0 + p) * 64 + lane];
        cv = sigmoidf(gf[p] + bf) * cv + sigmoidf(gi[p] + bi) * tanhf(gg[p] + bg);
        float hnew = sigmoidf(go[p] + bo) * tanhf(cv);
        cl[(g0 + p) * 64 + lane] = cv;
        hl[(g0 + p) * 64 + lane] = hnew;
    }
}

// -------- fused attention: block(256)=4 waves per graph, online softmax ---------
__global__ __launch_bounds__(256) void k_pool(const float* __restrict__ h,
    const float* __restrict__ hl,
    const int* __restrict__ gstart, const int* __restrict__ gend,
    float* __restrict__ qstar)
{
    __shared__ float sq[64];
    __shared__ float sm[4], sl[4];
    __shared__ float sr[4][64];
    int g = blockIdx.x;
    int t = threadIdx.x, w = t >> 6, lane = t & 63;
    if (t < 64) sq[t] = hl[g * 64 + t];
    __syncthreads();
    int s = gstart[g], e = gend[g];
    float qv = sq[lane];
    float M = -3.4e38f, l = 0.f, r = 0.f;
    for (int n = s + w; n < e; n += 4) {
        float hvv = h[n * 64 + lane];
        float p = hvv * qv;
#pragma unroll
        for (int off = 32; off > 0; off >>= 1) p += __shfl_xor(p, off, 64);
        if (p > M) {
            float sc = __expf(M - p);
            l = l * sc + 1.f;
            r = r * sc + hvv;
            M = p;
        } else {
            float pe = __expf(p - M);
            l += pe;
            r += pe * hvv;
        }
    }
    if (lane == 0) { sm[w] = M; sl[w] = l; }
    sr[w][lane] = r;
    __syncthreads();
    if (w == 0) {
        float Mg = fmaxf(fmaxf(sm[0], sm[1]), fmaxf(sm[2], sm[3]));
        float lg = 0.f, rg = 0.f;
#pragma unroll
        for (int wp = 0; wp < 4; ++wp) {
            float sc = __expf(sm[wp] - Mg);
            lg += sl[wp] * sc;
            rg += sr[wp][lane] * sc;
        }
        float inv = (lg > 0.f) ? 1.f / lg : 0.f;
        qstar[g * 128 + lane] = sq[lane];
        qstar[g * 128 + 64 + lane] = rg * inv;
    }
}

// ---------------- readout: 8 graphs/wave ----------------------------------------
__global__ __launch_bounds__(256) void k_readout(const float* __restrict__ qstar,
    const float* __restrict__ WT1, const float* __restrict__ b1,
    const float* __restrict__ W2, const float* __restrict__ b2,
    float* __restrict__ outp)
{
    int wid = (blockIdx.x * blockDim.x + threadIdx.x) >> 6;
    int lane = threadIdx.x & 63;
    if (wid >= NGR / 8) return;
    int g0 = wid * 8;
    float q0[8], q1[8], acc[8];
#pragma unroll
    for (int p = 0; p < 8; ++p) {
        q0[p] = qstar[(g0 + p) * 128 + lane];
        q1[p] = qstar[(g0 + p) * 128 + 64 + lane];
        acc[p] = b1[lane];
    }
#pragma unroll 2
    for (int j = 0; j < 64; ++j) {
        float w0v = WT1[j * 64 + lane];
        float w1v = WT1[(64 + j) * 64 + lane];
#pragma unroll
        for (int p = 0; p < 8; ++p)
            acc[p] += __shfl(q0[p], j, 64) * w0v + __shfl(q1[p], j, 64) * w1v;
    }
    float w2 = W2[lane], b2v = b2[0];
#pragma unroll
    for (int p = 0; p < 8; ++p) {
        float pr = fmaxf(acc[p], 0.f) * w2;
#pragma unroll
        for (int off = 32; off > 0; off >>= 1) pr += __shfl_xor(pr, off, 64);
        if (lane == 0) outp[g0 + p] = pr + b2v;
    }
}

extern "C" void kernel_launch(void* const* d_in, const int* in_sizes, int n_in,
                              void* d_out, int out_size, void* d_ws, size_t ws_size,
                              hipStream_t stream)
{
    const float* x      = (const float*)d_in[0];
    const float* ea     = (const float*)d_in[1];
    const int*   ei     = (const int*)d_in[2];
    const int*   batch  = (const int*)d_in[3];
    const float* W0     = (const float*)d_in[4];
    const float* b0     = (const float*)d_in[5];
    const float* We1    = (const float*)d_in[6];
    const float* be1    = (const float*)d_in[7];
    const float* We2    = (const float*)d_in[8];
    const float* be2    = (const float*)d_in[9];
    const float* b_conv = (const float*)d_in[10];
    const float* W_ih   = (const float*)d_in[11];
    const float* W_hh   = (const float*)d_in[12];
    const float* b_ih   = (const float*)d_in[13];
    const float* b_hh   = (const float*)d_in[14];
    const float* W_ihl  = (const float*)d_in[15];
    const float* W_hhl  = (const float*)d_in[16];
    const float* b_ihl  = (const float*)d_in[17];
    const float* b_hhl  = (const float*)d_in[18];
    const float* W1     = (const float*)d_in[19];
    const float* b1     = (const float*)d_in[20];
    const float* W2     = (const float*)d_in[21];
    const float* b2     = (const float*)d_in[22];
    float* outp = (float*)d_out;

    char* ws = (char*)d_ws;
    size_t off = 0;
    auto alloc = [&](size_t bytes) -> char* {
        char* p = ws + off;
        off += (bytes + 255) & ~(size_t)255;
        return p;
    };
    u16*   h1     = (u16*)  alloc((size_t)NE * 128 * 2);        // 10.24 MB
    u16*   Wt     = (u16*)  alloc((size_t)64 * WT_STRIDE * 2);  // 1.06 MB
    u16*   outb   = (u16*)  alloc((size_t)NN * 64 * 2);         // 2.56 MB
    float* h      = (float*)alloc((size_t)NN * 64 * 4);         // 5.12 MB
    float* pbuf   = (float*)alloc((size_t)NE * KH * 64 * 4);    // 20.48 MB
    int*   rowptr = (int*)  alloc((NN + 1) * 4);
    int*   eids   = (int*)  alloc(NE * 4);
    int*   cnt    = (int*)  alloc(NN * 4);       // cnt..gend contiguous, one memset
    int*   cur    = (int*)  alloc(NN * 4);
    int*   gstart = (int*)  alloc(NGR * 4);
    int*   gend   = (int*)  alloc(NGR * 4);
    float* hl     = (float*)alloc(NGR * 64 * 4);
    float* cl     = (float*)alloc(NGR * 64 * 4);
    float* qstar  = (float*)alloc(NGR * 128 * 4);
    float* WTih   = (float*)alloc(12288 * 4);
    float* WThh   = (float*)alloc(12288 * 4);
    float* WTihl  = (float*)alloc(32768 * 4);
    float* WThhl  = (float*)alloc(16384 * 4);
    float* WT1    = (float*)alloc(8192 * 4);
    if (off > ws_size) return;   // ~41.5 MB needed

    size_t zspan = (size_t)((char*)(gend + NGR) - (char*)cnt);
    hipMemsetAsync(cnt, 0, zspan, stream);

    k_pre<<<1152, 256, 0, stream>>>(x, ea, ei, batch, W0, b0, We1, be1, We2, be2,
                                    W_ih, W_hh, W_ihl, W_hhl, W1,
                                    h, outb, h1, Wt, cnt, gstart, gend,
                                    WTih, WThh, WTihl, WThhl, WT1, hl, cl, qstar);
    k_scan<<<1, 1024, 0, stream>>>(cnt, rowptr);
    k_scatter<<<64, 256, 0, stream>>>(ei, rowptr, cur, eids);

    dim3 mgrid(313, KH, 1);
    for (int it = 0; it < 3; ++it) {
        k_msg<<<mgrid, 128, 0, stream>>>(outb, h1, Wt, ei, pbuf);
        k_gru<<<625, 256, 0, stream>>>(h, outb, pbuf, rowptr, eids, b_conv,
                                       WTih, WThh, b_ih, b_hh);
    }
    for (int st = 0; st < 3; ++st) {
        k_lstm<<<32, 256, 0, stream>>>(hl, cl, qstar, WTihl, WThhl, b_ihl, b_hhl);
        k_pool<<<NGR, 256, 0, stream>>>(h, hl, gstart, gend, qstar);
    }
    k_readout<<<32, 256, 0, stream>>>(qstar, WT1, b1, W2, b2, outp);
}

// Round 6
// 756.065 us; speedup vs baseline: 1.1135x; 1.1135x over previous
//
#include <hip/hip_runtime.h>

#define NN 20000
#define NE 40000
#define NGR 1000
#define KH 4                      // K-split for k_msg; pbuf stride = KH*64
#define WTF_BIAS 524288           // u16 offset of bias frags in WtF

typedef unsigned short u16;
typedef u16 u16x8 __attribute__((ext_vector_type(8)));
typedef __bf16 bf16x8 __attribute__((ext_vector_type(8)));
typedef float f32x4 __attribute__((ext_vector_type(4)));

union U8 { u16x8 u; bf16x8 b; };

__device__ __forceinline__ u16 f2bf(float f) {
    union { float f; unsigned u; } v; v.f = f;
    unsigned r = v.u + 0x7FFF + ((v.u >> 16) & 1);   // RNE
    return (u16)(r >> 16);
}
__device__ __forceinline__ float bf2f(u16 h) {
    union { unsigned u; float f; } v; v.u = ((unsigned)h) << 16;
    return v.f;
}
__device__ __forceinline__ float sigmoidf(float x) { return 1.f / (1.f + __expf(-x)); }

// ============ fused one-time preamble, 1024 blocks, role by blockIdx range ======
// [0,64) transposes | [64,320) lin0 | [320,832) edge_mlp | [832,960) WtF gen
// [960,992) degree cnt | [992,1024) graph ranges
__global__ __launch_bounds__(256) void k_pre(
    const float* __restrict__ x, const float* __restrict__ ea,
    const int* __restrict__ ei, const int* __restrict__ batch,
    const float* __restrict__ W0, const float* __restrict__ b0,
    const float* __restrict__ We1, const float* __restrict__ be1,
    const float* __restrict__ We2, const float* __restrict__ be2,
    const float* __restrict__ W_ih, const float* __restrict__ W_hh,
    const float* __restrict__ W_ihl, const float* __restrict__ W_hhl,
    const float* __restrict__ W1,
    float* __restrict__ h, u16* __restrict__ outb, u16* __restrict__ h1,
    u16* __restrict__ WtF, int* __restrict__ cnt,
    int* __restrict__ gstart, int* __restrict__ gend,
    float* __restrict__ WTih, float* __restrict__ WThh,
    float* __restrict__ WTihl, float* __restrict__ WThhl, float* __restrict__ WT1)
{
    const int b = blockIdx.x;
    const int t = threadIdx.x;

    if (b < 64) {                                    // transposes (81920 elements)
        for (int idx = b * 256 + t; idx < 81920; idx += 64 * 256) {
            int i = idx;
            if (i < 12288) { WTih[i] = W_ih[(i % 192) * 64 + i / 192]; continue; }
            i -= 12288;
            if (i < 12288) { WThh[i] = W_hh[(i % 192) * 64 + i / 192]; continue; }
            i -= 12288;
            if (i < 32768) { WTihl[i] = W_ihl[(i % 256) * 128 + i / 256]; continue; }
            i -= 32768;
            if (i < 16384) { WThhl[i] = W_hhl[(i % 256) * 64 + i / 256]; continue; }
            i -= 16384;
            WT1[i] = W1[(i % 64) * 128 + i / 64];
        }
        return;
    }
    if (b < 320) {                                   // lin0, 1024 waves grid-stride
        int wv = (b - 64) * 4 + (t >> 6);
        int lane = t & 63;
        float w0r[32];
#pragma unroll
        for (int f = 0; f < 32; ++f) w0r[f] = W0[lane * 32 + f];
        float b0v = b0[lane];
        for (int n = wv; n < NN; n += 1024) {
            float xv = (lane < 32) ? x[n * 32 + lane] : 0.f;
            float acc = b0v;
#pragma unroll
            for (int f = 0; f < 32; ++f) acc += __shfl(xv, f, 64) * w0r[f];
            float rv = fmaxf(acc, 0.f);
            h[n * 64 + lane] = rv;
            outb[n * 64 + lane] = f2bf(rv);
        }
        return;
    }
    if (b < 832) {                                   // edge MLP over NE*128
        for (int idx = (b - 320) * 256 + t; idx < NE * 128; idx += 512 * 256) {
            int e = idx >> 7, k = idx & 127;
            float acc = be1[k];
#pragma unroll
            for (int j = 0; j < 5; ++j)
                acc += ea[e * 5 + j] * We1[k * 5 + j];
            h1[idx] = f2bf(fmaxf(acc, 0.f));
        }
        return;
    }
    if (b < 960) {                                   // WtF: frag-major B for k_msg
        for (int idx = (b - 832) * 256 + t; idx < WTF_BIAS + 4096; idx += 128 * 256) {
            float v;
            if (idx < WTF_BIAS) {
                int j = idx & 7, lane = (idx >> 3) & 63;
                int nt = (idx >> 9) & 3, s4 = (idx >> 11) & 3, ch = idx >> 13;
                int o = nt * 16 + (lane & 15);
                int k = s4 * 32 + (lane >> 4) * 8 + j;
                v = We2[(size_t)(ch * 64 + o) * 128 + k];
            } else {
                int bидx = idx - WTF_BIAS;
                int j = bидx & 7, lane = (bидx >> 3) & 63;
                int nt = (bидx >> 9) & 3, sb = bидx >> 11;
                int o = nt * 16 + (lane & 15);
                int i = sb * 32 + (lane >> 4) * 8 + j;
                v = be2[i * 64 + o];
            }
            WtF[idx] = f2bf(v);
        }
        return;
    }
    if (b < 992) {                                   // degree count
        for (int e = (b - 960) * 256 + t; e < NE; e += 32 * 256)
            atomicAdd(&cnt[ei[NE + e]], 1);
        return;
    }
    {                                                // graph ranges (batch sorted)
        for (int idx = (b - 992) * 256 + t; idx < NN; idx += 32 * 256) {
            int bg = batch[idx];
            if (idx == 0 || batch[idx - 1] != bg) gstart[bg] = idx;
            if (idx == NN - 1 || batch[idx + 1] != bg) gend[bg] = idx + 1;
        }
    }
}

// ---------------- exclusive prefix over cnt -> rowptr[NN+1], one block ----------
__global__ __launch_bounds__(1024) void k_scan(const int* __restrict__ cnt,
                                               int* __restrict__ rowptr)
{
    __shared__ int ps[1024];
    int t = threadIdx.x;
    int base = t * 20;
    int loc[20];
    int s = 0;
#pragma unroll
    for (int i = 0; i < 20; ++i) {
        int idx = base + i;
        loc[i] = s;
        s += (idx < NN) ? cnt[idx] : 0;
    }
    ps[t] = s;
    __syncthreads();
    for (int off = 1; off < 1024; off <<= 1) {
        int v = (t >= off) ? ps[t - off] : 0;
        __syncthreads();
        ps[t] += v;
        __syncthreads();
    }
    int ex = (t > 0) ? ps[t - 1] : 0;
#pragma unroll
    for (int i = 0; i < 20; ++i) {
        int idx = base + i;
        if (idx < NN) rowptr[idx] = ex + loc[i];
    }
    if (t == 1023) rowptr[NN] = ps[1023];
}

// ---------------- scatter edge ids into CSR ----------------
__global__ __launch_bounds__(256) void k_scatter(const int* __restrict__ ei,
    const int* __restrict__ rowptr, int* __restrict__ cur, int* __restrict__ eids)
{
    for (int e = blockIdx.x * 256 + threadIdx.x; e < NE; e += gridDim.x * 256) {
        int d = ei[NE + e];
        int pos = atomicAdd(&cur[d], 1);
        eids[rowptr[d] + pos] = e;
    }
}

// ---------------- message GEMM: frag-major B, barrier-free K-loop ---------------
// pbuf[e][kh][o] (bf16) = sum_{ch in slice} sv[e,ch]*(h1[e,:] . We2-chunk)
// B-frags: coalesced 1KB loads from WtF (L2-resident, pre-swizzled). No LDS-B.
__global__ __launch_bounds__(128, 2) void k_msg(
    const u16* __restrict__ outb, const u16* __restrict__ h1,
    const u16* __restrict__ WtF, const int* __restrict__ ei,
    u16* __restrict__ pbuf)
{
    __shared__ __align__(16) u16 sh[128 * 72];   // sv rows (out[src]) bf16
    const int t = threadIdx.x;
    const int eb0 = blockIdx.x * 128;
    const int kh = blockIdx.y;                   // 0..KH-1

#pragma unroll
    for (int r = 0; r < 8; ++r) {                // gather out[src]: 128 rows
        int cid = t + 128 * r;
        int row = cid >> 3, c8 = cid & 7;
        int e = eb0 + row;
        u16x8 v = {};
        if (e < NE) { int s = ei[e]; v = *(const u16x8*)(outb + (size_t)s * 64 + c8 * 8); }
        *(u16x8*)&sh[row * 72 + c8 * 8] = v;
    }

    const int lane = t & 63, w = t >> 6, r16 = lane & 15, q = lane >> 4;
    const int w64 = w * 64;

    // static A-fragments: h1 rows, reused across all chunks
    u16x8 h1r[4][4];
#pragma unroll
    for (int sub = 0; sub < 4; ++sub) {
        int e = eb0 + w64 + sub * 16 + r16;
        if (e >= NE) e = NE - 1;                 // contribution zeroed via sv=0
        const u16* hp = h1 + (size_t)e * 128 + q * 8;
#pragma unroll
        for (int s4 = 0; s4 < 4; ++s4)
            h1r[sub][s4] = *(const u16x8*)(hp + s4 * 32);
    }

    f32x4 acc[4][4];
    const f32x4 z4 = {0.f, 0.f, 0.f, 0.f};
#pragma unroll
    for (int sub = 0; sub < 4; ++sub)
#pragma unroll
        for (int nt = 0; nt < 4; ++nt) acc[sub][nt] = z4;
    __syncthreads();                             // the ONLY barrier

#pragma unroll 1
    for (int cc = 0; cc < 16; ++cc) {
        const int ch = kh * 16 + cc;
        const u16* wp = WtF + (size_t)ch * 8192 + lane * 8;  // 16 frags x 512 u16

        f32x4 P[4][4];
#pragma unroll
        for (int sub = 0; sub < 4; ++sub)
#pragma unroll
            for (int nt = 0; nt < 4; ++nt) P[sub][nt] = z4;

#pragma unroll
        for (int s4 = 0; s4 < 4; ++s4) {
            U8 bv[4];
#pragma unroll
            for (int nt = 0; nt < 4; ++nt)
                bv[nt].u = *(const u16x8*)(wp + (s4 * 4 + nt) * 512);
#pragma unroll
            for (int sub = 0; sub < 4; ++sub) {
                U8 a; a.u = h1r[sub][s4];
#pragma unroll
                for (int nt = 0; nt < 4; ++nt)
                    P[sub][nt] = __builtin_amdgcn_mfma_f32_16x16x32_bf16(
                        a.b, bv[nt].b, P[sub][nt], 0, 0, 0);
            }
        }
        // scale by sv (row m = w64 + sub*16 + q*4 + r) and accumulate
#pragma unroll
        for (int sub = 0; sub < 4; ++sub) {
            int mb = w64 + sub * 16 + q * 4;
            float s0 = bf2f(sh[(mb + 0) * 72 + ch]);
            float s1 = bf2f(sh[(mb + 1) * 72 + ch]);
            float s2 = bf2f(sh[(mb + 2) * 72 + ch]);
            float s3 = bf2f(sh[(mb + 3) * 72 + ch]);
#pragma unroll
            for (int nt = 0; nt < 4; ++nt) {
                acc[sub][nt][0] += s0 * P[sub][nt][0];
                acc[sub][nt][1] += s1 * P[sub][nt][1];
                acc[sub][nt][2] += s2 * P[sub][nt][2];
                acc[sub][nt][3] += s3 * P[sub][nt][3];
            }
        }
    }

    if (kh == KH - 1) {   // bias block: A = out[src], B = be2 frags
        U8 bvb[2][4];
#pragma unroll
        for (int sb = 0; sb < 2; ++sb)
#pragma unroll
            for (int nt = 0; nt < 4; ++nt)
                bvb[sb][nt].u = *(const u16x8*)(WtF + WTF_BIAS + ((sb * 4 + nt) * 64 + lane) * 8);
#pragma unroll
        for (int sub = 0; sub < 4; ++sub) {
            int m = w64 + sub * 16 + r16;
#pragma unroll
            for (int sb = 0; sb < 2; ++sb) {
                U8 a; a.u = *(const u16x8*)&sh[m * 72 + sb * 32 + q * 8];
#pragma unroll
                for (int nt = 0; nt < 4; ++nt)
                    acc[sub][nt] = __builtin_amdgcn_mfma_f32_16x16x32_bf16(
                        a.b, bvb[sb][nt].b, acc[sub][nt], 0, 0, 0);
            }
        }
    }

    // coalesced-ish bf16 stores: pbuf[e][kh][o]
#pragma unroll
    for (int sub = 0; sub < 4; ++sub) {
#pragma unroll
        for (int r = 0; r < 4; ++r) {
            int e = eb0 + w64 + sub * 16 + q * 4 + r;
            if (e >= NE) continue;
            u16* pp = pbuf + (size_t)e * (KH * 64) + kh * 64 + r16;
#pragma unroll
            for (int nt = 0; nt < 4; ++nt)
                pp[nt * 16] = f2bf(acc[sub][nt][r]);
        }
    }
}

// -------- GRU cell: CSR aggregation + deg-norm + gates, 16 nodes/wave ------------
__global__ __launch_bounds__(256) void k_gru(float* __restrict__ h, u16* __restrict__ outb,
    const u16* __restrict__ pbuf, const int* __restrict__ rowptr,
    const int* __restrict__ eids, const float* __restrict__ b_conv,
    const float* __restrict__ WTih, const float* __restrict__ WThh,
    const float* __restrict__ b_ih, const float* __restrict__ b_hh)
{
    int wid = (blockIdx.x * blockDim.x + threadIdx.x) >> 6;
    int lane = threadIdx.x & 63;
    int n0 = wid * 16;
    if (n0 >= NN) return;
    float bcv = b_conv[lane];
    float m[16], hv[16];
#pragma unroll
    for (int p = 0; p < 16; ++p) {
        int n = n0 + p;
        int rs = rowptr[n], re = rowptr[n + 1];
        float v = 0.f;
        for (int j = rs; j < re; ++j) {
            const u16* pb = pbuf + (size_t)eids[j] * (KH * 64);
            v += bf2f(pb[lane]) + bf2f(pb[64 + lane])
               + bf2f(pb[128 + lane]) + bf2f(pb[192 + lane]);
        }
        float invd = 1.f / fmaxf((float)(re - rs), 1.f);
        m[p] = fmaxf(v * invd + bcv, 0.f);
        hv[p] = h[n * 64 + lane];
    }
    float air[16] = {}, aiz[16] = {}, ain[16] = {};
    float ahr[16] = {}, ahz[16] = {}, ahn[16] = {};
#pragma unroll 2
    for (int i = 0; i < 64; ++i) {
        const float* wi = WTih + i * 192;
        const float* wh = WThh + i * 192;
        float wir = wi[lane], wiz = wi[64 + lane], win = wi[128 + lane];
        float whr = wh[lane], whz = wh[64 + lane], whn = wh[128 + lane];
#pragma unroll
        for (int p = 0; p < 16; ++p) {
            float mi = __shfl(m[p], i, 64);
            float hi = __shfl(hv[p], i, 64);
            air[p] += mi * wir; aiz[p] += mi * wiz; ain[p] += mi * win;
            ahr[p] += hi * whr; ahz[p] += hi * whz; ahn[p] += hi * whn;
        }
    }
    float bir = b_ih[lane], biz = b_ih[64 + lane], bin = b_ih[128 + lane];
    float bhr = b_hh[lane], bhz = b_hh[64 + lane], bhn = b_hh[128 + lane];
#pragma unroll
    for (int p = 0; p < 16; ++p) {
        float r = sigmoidf(air[p] + bir + ahr[p] + bhr);
        float z = sigmoidf(aiz[p] + biz + ahz[p] + bhz);
        float nng = tanhf(ain[p] + bin + r * (ahn[p] + bhn));
        float hnew = (1.f - z) * nng + z * hv[p];
        h[(n0 + p) * 64 + lane] = hnew;
        outb[(n0 + p) * 64 + lane] = f2bf(hnew);
    }
}

// -------- fused Set2Set: 3x(LSTM + attention) + readout, 8 graphs/block ----------
__global__ __launch_bounds__(256) void k_s2s(const float* __restrict__ h,
    const int* __restrict__ gstart, const int* __restrict__ gend,
    const float* __restrict__ WTihl, const float* __restrict__ WThhl,
    const float* __restrict__ b_ihl, const float* __restrict__ b_hhl,
    const float* __restrict__ WT1, const float* __restrict__ b1,
    const float* __restrict__ W2, const float* __restrict__ b2,
    float* __restrict__ outp)
{
    __shared__ float qs[8][128];    // q_star
    __shared__ float hlL[8][64];
    __shared__ float clL[8][64];
    __shared__ float gt[8][256];
    const int g0 = blockIdx.x * 8;
    const int t = threadIdx.x, w = t >> 6, lane = t & 63;

    for (int i = t; i < 8 * 128; i += 256) ((float*)qs)[i] = 0.f;
    for (int i = t; i < 8 * 64; i += 256) { ((float*)hlL)[i] = 0.f; ((float*)clL)[i] = 0.f; }
    __syncthreads();

    for (int step = 0; step < 3; ++step) {
        // ---- LSTM gates: wave w computes outputs o = w*64 + lane ----
        const int o = w * 64 + lane;
        float q0[8], q1[8], hv8[8], ga[8];
        float bi = b_ihl[o] + b_hhl[o];
#pragma unroll
        for (int g = 0; g < 8; ++g) {
            q0[g] = qs[g][lane]; q1[g] = qs[g][64 + lane]; hv8[g] = hlL[g][lane];
            ga[g] = bi;
        }
#pragma unroll 2
        for (int j = 0; j < 64; ++j) {
            float wv  = WTihl[j * 256 + o];
            float wv2 = WTihl[(64 + j) * 256 + o];
            float wv3 = WThhl[j * 256 + o];
#pragma unroll
            for (int g = 0; g < 8; ++g)
                ga[g] += __shfl(q0[g], j, 64) * wv + __shfl(q1[g], j, 64) * wv2
                       + __shfl(hv8[g], j, 64) * wv3;
        }
#pragma unroll
        for (int g = 0; g < 8; ++g) gt[g][o] = ga[g];
        __syncthreads();
        // ---- cell update (512 items over 256 threads) ----
        for (int it = t; it < 512; it += 256) {
            int g = it >> 6, d = it & 63;
            float cv = sigmoidf(gt[g][64 + d]) * clL[g][d]
                     + sigmoidf(gt[g][d]) * tanhf(gt[g][128 + d]);
            float hn = sigmoidf(gt[g][192 + d]) * tanhf(cv);
            clL[g][d] = cv; hlL[g][d] = hn; qs[g][d] = hn;
        }
        __syncthreads();
        // ---- attention: wave w handles graphs w*2, w*2+1 ----
#pragma unroll
        for (int gg = 0; gg < 2; ++gg) {
            int g = w * 2 + gg;
            int s = gstart[g0 + g], e = gend[g0 + g];
            float qv = hlL[g][lane];
            float M = -3.4e38f, l = 0.f, r = 0.f;
            for (int n = s; n < e; ++n) {
                float hvv = h[n * 64 + lane];
                float p = hvv * qv;
#pragma unroll
                for (int off = 32; off > 0; off >>= 1) p += __shfl_xor(p, off, 64);
                if (p > M) {
                    float sc = __expf(M - p);
                    l = l * sc + 1.f;
                    r = r * sc + hvv;
                    M = p;
                } else {
                    float pe = __expf(p - M);
                    l += pe;
                    r += pe * hvv;
                }
            }
            float inv = (l > 0.f) ? 1.f / l : 0.f;
            qs[g][64 + lane] = r * inv;
        }
        __syncthreads();
    }
    // ---- readout: wave w handles graphs w*2, w*2+1 ----
#pragma unroll
    for (int gg = 0; gg < 2; ++gg) {
        int g = w * 2 + gg;
        float acc = b1[lane];
#pragma unroll 4
        for (int j = 0; j < 128; ++j)
            acc += qs[g][j] * WT1[j * 64 + lane];
        float pr = fmaxf(acc, 0.f) * W2[lane];
#pragma unroll
        for (int off = 32; off > 0; off >>= 1) pr += __shfl_xor(pr, off, 64);
        if (lane == 0) outp[g0 + g] = pr + b2[0];
    }
}

extern "C" void kernel_launch(void* const* d_in, const int* in_sizes, int n_in,
                              void* d_out, int out_size, void* d_ws, size_t ws_size,
                              hipStream_t stream)
{
    const float* x      = (const float*)d_in[0];
    const float* ea     = (const float*)d_in[1];
    const int*   ei     = (const int*)d_in[2];
    const int*   batch  = (const int*)d_in[3];
    const float* W0     = (const float*)d_in[4];
    const float* b0     = (const float*)d_in[5];
    const float* We1    = (const float*)d_in[6];
    const float* be1    = (const float*)d_in[7];
    const float* We2    = (const float*)d_in[8];
    const float* be2    = (const float*)d_in[9];
    const float* b_conv = (const float*)d_in[10];
    const float* W_ih   = (const float*)d_in[11];
    const float* W_hh   = (const float*)d_in[12];
    const float* b_ih   = (const float*)d_in[13];
    const float* b_hh   = (const float*)d_in[14];
    const float* W_ihl  = (const float*)d_in[15];
    const float* W_hhl  = (const float*)d_in[16];
    const float* b_ihl  = (const float*)d_in[17];
    const float* b_hhl  = (const float*)d_in[18];
    const float* W1     = (const float*)d_in[19];
    const float* b1     = (const float*)d_in[20];
    const float* W2     = (const float*)d_in[21];
    const float* b2     = (const float*)d_in[22];
    float* outp = (float*)d_out;

    char* ws = (char*)d_ws;
    size_t off = 0;
    auto alloc = [&](size_t bytes) -> char* {
        char* p = ws + off;
        off += (bytes + 255) & ~(size_t)255;
        return p;
    };
    u16*   h1     = (u16*)  alloc((size_t)NE * 128 * 2);       // 10.24 MB
    u16*   WtF    = (u16*)  alloc((WTF_BIAS + 4096) * 2);      // 1.06 MB
    u16*   outb   = (u16*)  alloc((size_t)NN * 64 * 2);        // 2.56 MB
    float* h      = (float*)alloc((size_t)NN * 64 * 4);        // 5.12 MB
    u16*   pbuf   = (u16*)  alloc((size_t)NE * KH * 64 * 2);   // 20.48 MB
    int*   rowptr = (int*)  alloc((NN + 1) * 4);
    int*   eids   = (int*)  alloc(NE * 4);
    int*   cnt    = (int*)  alloc(NN * 4);     // cnt..gend contiguous, one memset
    int*   cur    = (int*)  alloc(NN * 4);
    int*   gstart = (int*)  alloc(NGR * 4);
    int*   gend   = (int*)  alloc(NGR * 4);
    float* WTih   = (float*)alloc(12288 * 4);
    float* WThh   = (float*)alloc(12288 * 4);
    float* WTihl  = (float*)alloc(32768 * 4);
    float* WThhl  = (float*)alloc(16384 * 4);
    float* WT1    = (float*)alloc(8192 * 4);
    if (off > ws_size) return;   // ~40.5 MB needed

    size_t zspan = (size_t)((char*)(gend + NGR) - (char*)cnt);
    hipMemsetAsync(cnt, 0, zspan, stream);

    k_pre<<<1024, 256, 0, stream>>>(x, ea, ei, batch, W0, b0, We1, be1, We2, be2,
                                    W_ih, W_hh, W_ihl, W_hhl, W1,
                                    h, outb, h1, WtF, cnt, gstart, gend,
                                    WTih, WThh, WTihl, WThhl, WT1);
    k_scan<<<1, 1024, 0, stream>>>(cnt, rowptr);
    k_scatter<<<64, 256, 0, stream>>>(ei, rowptr, cur, eids);

    dim3 mgrid(313, KH, 1);
    for (int it = 0; it < 3; ++it) {
        k_msg<<<mgrid, 128, 0, stream>>>(outb, h1, WtF, ei, pbuf);
        k_gru<<<313, 256, 0, stream>>>(h, outb, pbuf, rowptr, eids, b_conv,
                                       WTih, WThh, b_ih, b_hh);
    }
    k_s2s<<<NGR / 8, 256, 0, stream>>>(h, gstart, gend, WTihl, WThhl, b_ihl, b_hhl,
                                       WT1, b1, W2, b2, outp);
}

// Round 7
// 606.468 us; speedup vs baseline: 1.3882x; 1.2467x over previous
//
#include <hip/hip_runtime.h>

#define NN 20000
#define NE 40000
#define NGR 1000
#define KH 4                      // K-split for k_msg; pbuf stride = KH*64
#define WTF_BIAS 524288           // u16 offset of bias frags in WtF

typedef unsigned short u16;
typedef u16 u16x8 __attribute__((ext_vector_type(8)));
typedef __bf16 bf16x8 __attribute__((ext_vector_type(8)));
typedef float f32x4 __attribute__((ext_vector_type(4)));

union U8 { u16x8 u; bf16x8 b; };

__device__ __forceinline__ u16 f2bf(float f) {
    union { float f; unsigned u; } v; v.f = f;
    unsigned r = v.u + 0x7FFF + ((v.u >> 16) & 1);   // RNE
    return (u16)(r >> 16);
}
__device__ __forceinline__ float bf2f(u16 h) {
    union { unsigned u; float f; } v; v.u = ((unsigned)h) << 16;
    return v.f;
}
__device__ __forceinline__ float sigmoidf(float x) { return 1.f / (1.f + __expf(-x)); }

// ============ fused one-time preamble, 1024 blocks, role by blockIdx range ======
__global__ __launch_bounds__(256) void k_pre(
    const float* __restrict__ x, const float* __restrict__ ea,
    const int* __restrict__ ei, const int* __restrict__ batch,
    const float* __restrict__ W0, const float* __restrict__ b0,
    const float* __restrict__ We1, const float* __restrict__ be1,
    const float* __restrict__ We2, const float* __restrict__ be2,
    const float* __restrict__ W_ih, const float* __restrict__ W_hh,
    const float* __restrict__ W_ihl, const float* __restrict__ W_hhl,
    const float* __restrict__ W1,
    float* __restrict__ h, u16* __restrict__ outb, u16* __restrict__ h1,
    u16* __restrict__ WtF, int* __restrict__ cnt,
    int* __restrict__ gstart, int* __restrict__ gend,
    float* __restrict__ WTih, float* __restrict__ WThh,
    float* __restrict__ WTihl, float* __restrict__ WThhl, float* __restrict__ WT1)
{
    const int b = blockIdx.x;
    const int t = threadIdx.x;

    if (b < 64) {                                    // transposes (81920 elements)
        for (int idx = b * 256 + t; idx < 81920; idx += 64 * 256) {
            int i = idx;
            if (i < 12288) { WTih[i] = W_ih[(i % 192) * 64 + i / 192]; continue; }
            i -= 12288;
            if (i < 12288) { WThh[i] = W_hh[(i % 192) * 64 + i / 192]; continue; }
            i -= 12288;
            if (i < 32768) { WTihl[i] = W_ihl[(i % 256) * 128 + i / 256]; continue; }
            i -= 32768;
            if (i < 16384) { WThhl[i] = W_hhl[(i % 256) * 64 + i / 256]; continue; }
            i -= 16384;
            WT1[i] = W1[(i % 64) * 128 + i / 64];
        }
        return;
    }
    if (b < 320) {                                   // lin0, 1024 waves grid-stride
        int wv = (b - 64) * 4 + (t >> 6);
        int lane = t & 63;
        float w0r[32];
#pragma unroll
        for (int f = 0; f < 32; ++f) w0r[f] = W0[lane * 32 + f];
        float b0v = b0[lane];
        for (int n = wv; n < NN; n += 1024) {
            float xv = (lane < 32) ? x[n * 32 + lane] : 0.f;
            float acc = b0v;
#pragma unroll
            for (int f = 0; f < 32; ++f) acc += __shfl(xv, f, 64) * w0r[f];
            float rv = fmaxf(acc, 0.f);
            h[n * 64 + lane] = rv;
            outb[n * 64 + lane] = f2bf(rv);
        }
        return;
    }
    if (b < 832) {                                   // edge MLP over NE*128
        for (int idx = (b - 320) * 256 + t; idx < NE * 128; idx += 512 * 256) {
            int e = idx >> 7, k = idx & 127;
            float acc = be1[k];
#pragma unroll
            for (int j = 0; j < 5; ++j)
                acc += ea[e * 5 + j] * We1[k * 5 + j];
            h1[idx] = f2bf(fmaxf(acc, 0.f));
        }
        return;
    }
    if (b < 960) {                                   // WtF: frag-major B for k_msg
        for (int idx = (b - 832) * 256 + t; idx < WTF_BIAS + 4096; idx += 128 * 256) {
            float v;
            if (idx < WTF_BIAS) {
                int j = idx & 7, lane = (idx >> 3) & 63;
                int nt = (idx >> 9) & 3, s4 = (idx >> 11) & 3, ch = idx >> 13;
                int o = nt * 16 + (lane & 15);
                int k = s4 * 32 + (lane >> 4) * 8 + j;
                v = We2[(size_t)(ch * 64 + o) * 128 + k];
            } else {
                int bx = idx - WTF_BIAS;
                int j = bx & 7, lane = (bx >> 3) & 63;
                int nt = (bx >> 9) & 3, sb = bx >> 11;
                int o = nt * 16 + (lane & 15);
                int i = sb * 32 + (lane >> 4) * 8 + j;
                v = be2[i * 64 + o];
            }
            WtF[idx] = f2bf(v);
        }
        return;
    }
    if (b < 992) {                                   // degree count
        for (int e = (b - 960) * 256 + t; e < NE; e += 32 * 256)
            atomicAdd(&cnt[ei[NE + e]], 1);
        return;
    }
    {                                                // graph ranges (batch sorted)
        for (int idx = (b - 992) * 256 + t; idx < NN; idx += 32 * 256) {
            int bg = batch[idx];
            if (idx == 0 || batch[idx - 1] != bg) gstart[bg] = idx;
            if (idx == NN - 1 || batch[idx + 1] != bg) gend[bg] = idx + 1;
        }
    }
}

// ---------------- exclusive prefix over cnt -> rowptr[NN+1], one block ----------
__global__ __launch_bounds__(1024) void k_scan(const int* __restrict__ cnt,
                                               int* __restrict__ rowptr)
{
    __shared__ int ps[1024];
    int t = threadIdx.x;
    int base = t * 20;
    int loc[20];
    int s = 0;
#pragma unroll
    for (int i = 0; i < 20; ++i) {
        int idx = base + i;
        loc[i] = s;
        s += (idx < NN) ? cnt[idx] : 0;
    }
    ps[t] = s;
    __syncthreads();
    for (int off = 1; off < 1024; off <<= 1) {
        int v = (t >= off) ? ps[t - off] : 0;
        __syncthreads();
        ps[t] += v;
        __syncthreads();
    }
    int ex = (t > 0) ? ps[t - 1] : 0;
#pragma unroll
    for (int i = 0; i < 20; ++i) {
        int idx = base + i;
        if (idx < NN) rowptr[idx] = ex + loc[i];
    }
    if (t == 1023) rowptr[NN] = ps[1023];
}

// ---------------- scatter edge ids into CSR ----------------
__global__ __launch_bounds__(256) void k_scatter(const int* __restrict__ ei,
    const int* __restrict__ rowptr, int* __restrict__ cur, int* __restrict__ eids)
{
    for (int e = blockIdx.x * 256 + threadIdx.x; e < NE; e += gridDim.x * 256) {
        int d = ei[NE + e];
        int pos = atomicAdd(&cur[d], 1);
        eids[rowptr[d] + pos] = e;
    }
}

// ---------------- message GEMM: frag-major B, barrier-free K-loop ---------------
// 256 edges/block = 4 waves marching the same chunk stream (L1 reuse of B-frags).
__global__ __launch_bounds__(256, 2) void k_msg(
    const u16* __restrict__ outb, const u16* __restrict__ h1,
    const u16* __restrict__ WtF, const int* __restrict__ ei,
    u16* __restrict__ pbuf)
{
    __shared__ __align__(16) u16 sh[256 * 72];   // sv rows (out[src]) bf16
    const int t = threadIdx.x;
    const int eb0 = blockIdx.x * 256;
    const int kh = blockIdx.y;                   // 0..KH-1

#pragma unroll
    for (int r = 0; r < 8; ++r) {                // gather out[src]: 256 rows
        int cid = t + 256 * r;
        int row = cid >> 3, c8 = cid & 7;
        int e = eb0 + row;
        u16x8 v = {};
        if (e < NE) { int s = ei[e]; v = *(const u16x8*)(outb + (size_t)s * 64 + c8 * 8); }
        *(u16x8*)&sh[row * 72 + c8 * 8] = v;
    }

    const int lane = t & 63, w = t >> 6, r16 = lane & 15, q = lane >> 4;
    const int w64 = w * 64;

    // static A-fragments: h1 rows, reused across all chunks
    u16x8 h1r[4][4];
#pragma unroll
    for (int sub = 0; sub < 4; ++sub) {
        int e = eb0 + w64 + sub * 16 + r16;
        if (e >= NE) e = NE - 1;                 // contribution zeroed via sv=0
        const u16* hp = h1 + (size_t)e * 128 + q * 8;
#pragma unroll
        for (int s4 = 0; s4 < 4; ++s4)
            h1r[sub][s4] = *(const u16x8*)(hp + s4 * 32);
    }

    f32x4 acc[4][4];
    const f32x4 z4 = {0.f, 0.f, 0.f, 0.f};
#pragma unroll
    for (int sub = 0; sub < 4; ++sub)
#pragma unroll
        for (int nt = 0; nt < 4; ++nt) acc[sub][nt] = z4;
    __syncthreads();                             // the ONLY barrier

#pragma unroll 1
    for (int cc = 0; cc < 16; ++cc) {
        const int ch = kh * 16 + cc;
        const u16* wp = WtF + (size_t)ch * 8192 + lane * 8;  // 16 frags x 512 u16

        f32x4 P[4][4];
#pragma unroll
        for (int sub = 0; sub < 4; ++sub)
#pragma unroll
            for (int nt = 0; nt < 4; ++nt) P[sub][nt] = z4;

#pragma unroll
        for (int s4 = 0; s4 < 4; ++s4) {
            U8 bv[4];
#pragma unroll
            for (int nt = 0; nt < 4; ++nt)
                bv[nt].u = *(const u16x8*)(wp + (s4 * 4 + nt) * 512);
#pragma unroll
            for (int sub = 0; sub < 4; ++sub) {
                U8 a; a.u = h1r[sub][s4];
#pragma unroll
                for (int nt = 0; nt < 4; ++nt)
                    P[sub][nt] = __builtin_amdgcn_mfma_f32_16x16x32_bf16(
                        a.b, bv[nt].b, P[sub][nt], 0, 0, 0);
            }
        }
        // scale by sv (row m = w64 + sub*16 + q*4 + r) and accumulate
#pragma unroll
        for (int sub = 0; sub < 4; ++sub) {
            int mb = w64 + sub * 16 + q * 4;
            float s0 = bf2f(sh[(mb + 0) * 72 + ch]);
            float s1 = bf2f(sh[(mb + 1) * 72 + ch]);
            float s2 = bf2f(sh[(mb + 2) * 72 + ch]);
            float s3 = bf2f(sh[(mb + 3) * 72 + ch]);
#pragma unroll
            for (int nt = 0; nt < 4; ++nt) {
                acc[sub][nt][0] += s0 * P[sub][nt][0];
                acc[sub][nt][1] += s1 * P[sub][nt][1];
                acc[sub][nt][2] += s2 * P[sub][nt][2];
                acc[sub][nt][3] += s3 * P[sub][nt][3];
            }
        }
    }

    if (kh == KH - 1) {   // bias block: A = out[src], B = be2 frags
        U8 bvb[2][4];
#pragma unroll
        for (int sb = 0; sb < 2; ++sb)
#pragma unroll
            for (int nt = 0; nt < 4; ++nt)
                bvb[sb][nt].u = *(const u16x8*)(WtF + WTF_BIAS + ((sb * 4 + nt) * 64 + lane) * 8);
#pragma unroll
        for (int sub = 0; sub < 4; ++sub) {
            int m = w64 + sub * 16 + r16;
#pragma unroll
            for (int sb = 0; sb < 2; ++sb) {
                U8 a; a.u = *(const u16x8*)&sh[m * 72 + sb * 32 + q * 8];
#pragma unroll
                for (int nt = 0; nt < 4; ++nt)
                    acc[sub][nt] = __builtin_amdgcn_mfma_f32_16x16x32_bf16(
                        a.b, bvb[sb][nt].b, acc[sub][nt], 0, 0, 0);
            }
        }
    }

    // bf16 stores: pbuf[e][kh][o]
#pragma unroll
    for (int sub = 0; sub < 4; ++sub) {
#pragma unroll
        for (int r = 0; r < 4; ++r) {
            int e = eb0 + w64 + sub * 16 + q * 4 + r;
            if (e >= NE) continue;
            u16* pp = pbuf + (size_t)e * (KH * 64) + kh * 64 + r16;
#pragma unroll
            for (int nt = 0; nt < 4; ++nt)
                pp[nt * 16] = f2bf(acc[sub][nt][r]);
        }
    }
}

// -------- GRU cell: CSR aggregation + deg-norm + gates, 8 nodes/wave ------------
__global__ __launch_bounds__(256) void k_gru(float* __restrict__ h, u16* __restrict__ outb,
    const u16* __restrict__ pbuf, const int* __restrict__ rowptr,
    const int* __restrict__ eids, const float* __restrict__ b_conv,
    const float* __restrict__ WTih, const float* __restrict__ WThh,
    const float* __restrict__ b_ih, const float* __restrict__ b_hh)
{
    int wid = (blockIdx.x * blockDim.x + threadIdx.x) >> 6;
    int lane = threadIdx.x & 63;
    int n0 = wid * 8;
    if (n0 >= NN) return;
    float bcv = b_conv[lane];
    float m[8], hv[8];
#pragma unroll
    for (int p = 0; p < 8; ++p) {
        int n = n0 + p;
        int rs = rowptr[n], re = rowptr[n + 1];
        float v = 0.f;
        for (int j = rs; j < re; ++j) {
            const u16* pb = pbuf + (size_t)eids[j] * (KH * 64);
            v += bf2f(pb[lane]) + bf2f(pb[64 + lane])
               + bf2f(pb[128 + lane]) + bf2f(pb[192 + lane]);
        }
        float invd = 1.f / fmaxf((float)(re - rs), 1.f);
        m[p] = fmaxf(v * invd + bcv, 0.f);
        hv[p] = h[n * 64 + lane];
    }
    float air[8] = {}, aiz[8] = {}, ain[8] = {};
    float ahr[8] = {}, ahz[8] = {}, ahn[8] = {};
#pragma unroll 4
    for (int i = 0; i < 64; ++i) {
        const float* wi = WTih + i * 192;
        const float* wh = WThh + i * 192;
        float wir = wi[lane], wiz = wi[64 + lane], win = wi[128 + lane];
        float whr = wh[lane], whz = wh[64 + lane], whn = wh[128 + lane];
#pragma unroll
        for (int p = 0; p < 8; ++p) {
            float mi = __shfl(m[p], i, 64);
            float hi = __shfl(hv[p], i, 64);
            air[p] += mi * wir; aiz[p] += mi * wiz; ain[p] += mi * win;
            ahr[p] += hi * whr; ahz[p] += hi * whz; ahn[p] += hi * whn;
        }
    }
    float bir = b_ih[lane], biz = b_ih[64 + lane], bin = b_ih[128 + lane];
    float bhr = b_hh[lane], bhz = b_hh[64 + lane], bhn = b_hh[128 + lane];
#pragma unroll
    for (int p = 0; p < 8; ++p) {
        float r = sigmoidf(air[p] + bir + ahr[p] + bhr);
        float z = sigmoidf(aiz[p] + biz + ahz[p] + bhz);
        float nng = tanhf(ain[p] + bin + r * (ahn[p] + bhn));
        float hnew = (1.f - z) * nng + z * hv[p];
        h[(n0 + p) * 64 + lane] = hnew;
        outb[(n0 + p) * 64 + lane] = f2bf(hnew);
    }
}

// -------- fused Set2Set: 1 graph per block, 3x(LSTM + attention) + readout ------
__global__ __launch_bounds__(256) void k_s2s(const float* __restrict__ h,
    const int* __restrict__ gstart, const int* __restrict__ gend,
    const float* __restrict__ WTihl, const float* __restrict__ WThhl,
    const float* __restrict__ b_ihl, const float* __restrict__ b_hhl,
    const float* __restrict__ WT1, const float* __restrict__ b1,
    const float* __restrict__ W2, const float* __restrict__ b2,
    float* __restrict__ outp)
{
    __shared__ float qs[128];        // q_star for this graph
    __shared__ float hlL[64], clL[64];
    __shared__ float gt[256];
    __shared__ float sm[4], sl[4], sr[4][64];
    const int g = blockIdx.x;
    const int t = threadIdx.x, w = t >> 6, lane = t & 63;
    const int s = gstart[g], e = gend[g];

    if (t < 128) qs[t] = 0.f;
    if (t < 64) { hlL[t] = 0.f; clL[t] = 0.f; }
    __syncthreads();

    for (int step = 0; step < 3; ++step) {
        // ---- LSTM gates: thread t computes gate output o = t ----
        float ga = b_ihl[t] + b_hhl[t];
#pragma unroll 4
        for (int j = 0; j < 128; ++j)
            ga += qs[j] * WTihl[j * 256 + t];
#pragma unroll 4
        for (int j = 0; j < 64; ++j)
            ga += hlL[j] * WThhl[j * 256 + t];
        gt[t] = ga;
        __syncthreads();
        if (t < 64) {
            float cv = sigmoidf(gt[64 + t]) * clL[t] + sigmoidf(gt[t]) * tanhf(gt[128 + t]);
            float hn = sigmoidf(gt[192 + t]) * tanhf(cv);
            clL[t] = cv; hlL[t] = hn; qs[t] = hn;
        }
        __syncthreads();
        // ---- attention: 4 waves stride nodes, online softmax ----
        float qv = hlL[lane];
        float M = -3.4e38f, l = 0.f, r = 0.f;
        for (int n = s + w; n < e; n += 4) {
            float hvv = h[n * 64 + lane];
            float p = hvv * qv;
#pragma unroll
            for (int off = 32; off > 0; off >>= 1) p += __shfl_xor(p, off, 64);
            if (p > M) {
                float sc = __expf(M - p);
                l = l * sc + 1.f;
                r = r * sc + hvv;
                M = p;
            } else {
                float pe = __expf(p - M);
                l += pe;
                r += pe * hvv;
            }
        }
        if (lane == 0) { sm[w] = M; sl[w] = l; }
        sr[w][lane] = r;
        __syncthreads();
        if (w == 0) {
            float Mg = fmaxf(fmaxf(sm[0], sm[1]), fmaxf(sm[2], sm[3]));
            float lg = 0.f, rg = 0.f;
#pragma unroll
            for (int wp = 0; wp < 4; ++wp) {
                float sc = __expf(sm[wp] - Mg);     // finite sentinels: no NaN
                lg += sl[wp] * sc;
                rg += sr[wp][lane] * sc;
            }
            float inv = (lg > 0.f) ? 1.f / lg : 0.f;
            qs[64 + lane] = rg * inv;
        }
        __syncthreads();
    }
    // ---- readout: 4 waves split j, LDS reduce ----
    float acc = 0.f;
#pragma unroll 4
    for (int j = w * 32; j < w * 32 + 32; ++j)
        acc += qs[j] * WT1[j * 64 + lane];
    sr[w][lane] = acc;
    __syncthreads();
    if (w == 0) {
        float y = sr[0][lane] + sr[1][lane] + sr[2][lane] + sr[3][lane] + b1[lane];
        float pr = fmaxf(y, 0.f) * W2[lane];
#pragma unroll
        for (int off = 32; off > 0; off >>= 1) pr += __shfl_xor(pr, off, 64);
        if (lane == 0) outp[g] = pr + b2[0];
    }
}

extern "C" void kernel_launch(void* const* d_in, const int* in_sizes, int n_in,
                              void* d_out, int out_size, void* d_ws, size_t ws_size,
                              hipStream_t stream)
{
    const float* x      = (const float*)d_in[0];
    const float* ea     = (const float*)d_in[1];
    const int*   ei     = (const int*)d_in[2];
    const int*   batch  = (const int*)d_in[3];
    const float* W0     = (const float*)d_in[4];
    const float* b0     = (const float*)d_in[5];
    const float* We1    = (const float*)d_in[6];
    const float* be1    = (const float*)d_in[7];
    const float* We2    = (const float*)d_in[8];
    const float* be2    = (const float*)d_in[9];
    const float* b_conv = (const float*)d_in[10];
    const float* W_ih   = (const float*)d_in[11];
    const float* W_hh   = (const float*)d_in[12];
    const float* b_ih   = (const float*)d_in[13];
    const float* b_hh   = (const float*)d_in[14];
    const float* W_ihl  = (const float*)d_in[15];
    const float* W_hhl  = (const float*)d_in[16];
    const float* b_ihl  = (const float*)d_in[17];
    const float* b_hhl  = (const float*)d_in[18];
    const float* W1     = (const float*)d_in[19];
    const float* b1     = (const float*)d_in[20];
    const float* W2     = (const float*)d_in[21];
    const float* b2     = (const float*)d_in[22];
    float* outp = (float*)d_out;

    char* ws = (char*)d_ws;
    size_t off = 0;
    auto alloc = [&](size_t bytes) -> char* {
        char* p = ws + off;
        off += (bytes + 255) & ~(size_t)255;
        return p;
    };
    u16*   h1     = (u16*)  alloc((size_t)NE * 128 * 2);       // 10.24 MB
    u16*   WtF    = (u16*)  alloc((WTF_BIAS + 4096) * 2);      // 1.06 MB
    u16*   outb   = (u16*)  alloc((size_t)NN * 64 * 2);        // 2.56 MB
    float* h      = (float*)alloc((size_t)NN * 64 * 4);        // 5.12 MB
    u16*   pbuf   = (u16*)  alloc((size_t)NE * KH * 64 * 2);   // 20.48 MB
    int*   rowptr = (int*)  alloc((NN + 1) * 4);
    int*   eids   = (int*)  alloc(NE * 4);
    int*   cnt    = (int*)  alloc(NN * 4);     // cnt..gend contiguous, one memset
    int*   cur    = (int*)  alloc(NN * 4);
    int*   gstart = (int*)  alloc(NGR * 4);
    int*   gend   = (int*)  alloc(NGR * 4);
    float* WTih   = (float*)alloc(12288 * 4);
    float* WThh   = (float*)alloc(12288 * 4);
    float* WTihl  = (float*)alloc(32768 * 4);
    float* WThhl  = (float*)alloc(16384 * 4);
    float* WT1    = (float*)alloc(8192 * 4);
    if (off > ws_size) return;   // ~40.5 MB needed

    size_t zspan = (size_t)((char*)(gend + NGR) - (char*)cnt);
    hipMemsetAsync(cnt, 0, zspan, stream);

    k_pre<<<1024, 256, 0, stream>>>(x, ea, ei, batch, W0, b0, We1, be1, We2, be2,
                                    W_ih, W_hh, W_ihl, W_hhl, W1,
                                    h, outb, h1, WtF, cnt, gstart, gend,
                                    WTih, WThh, WTihl, WThhl, WT1);
    k_scan<<<1, 1024, 0, stream>>>(cnt, rowptr);
    k_scatter<<<64, 256, 0, stream>>>(ei, rowptr, cur, eids);

    dim3 mgrid((NE + 255) / 256, KH, 1);
    for (int it = 0; it < 3; ++it) {
        k_msg<<<mgrid, 256, 0, stream>>>(outb, h1, WtF, ei, pbuf);
        k_gru<<<625, 256, 0, stream>>>(h, outb, pbuf, rowptr, eids, b_conv,
                                       WTih, WThh, b_ih, b_hh);
    }
    k_s2s<<<NGR, 256, 0, stream>>>(h, gstart, gend, WTihl, WThhl, b_ihl, b_hhl,
                                   WT1, b1, W2, b2, outp);
}

// Round 8
// 598.949 us; speedup vs baseline: 1.4056x; 1.0126x over previous
//
#include <hip/hip_runtime.h>

#define NN 20000
#define NE 40000
#define NGR 1000
#define KH 4                      // K-split for k_msg; pbuf stride = KH*64
#define WTF_BIAS 524288           // u16 offset of bias frags in WtF

typedef unsigned short u16;
typedef unsigned int u32;
typedef u16 u16x8 __attribute__((ext_vector_type(8)));
typedef __bf16 bf16x8 __attribute__((ext_vector_type(8)));
typedef float f32x4 __attribute__((ext_vector_type(4)));

union U8 { u16x8 u; bf16x8 b; };

__device__ __forceinline__ u16 f2bf(float f) {
    union { float f; unsigned u; } v; v.f = f;
    unsigned r = v.u + 0x7FFF + ((v.u >> 16) & 1);   // RNE
    return (u16)(r >> 16);
}
__device__ __forceinline__ float bf2f(u16 h) {
    union { unsigned u; float f; } v; v.u = ((unsigned)h) << 16;
    return v.f;
}
__device__ __forceinline__ float sigmoidf(float x) { return 1.f / (1.f + __expf(-x)); }

// ============ fused one-time preamble, 1024 blocks, role by blockIdx range ======
__global__ __launch_bounds__(256) void k_pre(
    const float* __restrict__ x, const float* __restrict__ ea,
    const int* __restrict__ ei, const int* __restrict__ batch,
    const float* __restrict__ W0, const float* __restrict__ b0,
    const float* __restrict__ We1, const float* __restrict__ be1,
    const float* __restrict__ We2, const float* __restrict__ be2,
    const float* __restrict__ W_ih, const float* __restrict__ W_hh,
    const float* __restrict__ W_ihl, const float* __restrict__ W_hhl,
    const float* __restrict__ W1,
    float* __restrict__ h, u16* __restrict__ outb, u16* __restrict__ h1,
    u16* __restrict__ WtF, int* __restrict__ cnt,
    int* __restrict__ gstart, int* __restrict__ gend,
    float* __restrict__ WTih, float* __restrict__ WThh,
    float* __restrict__ WTihl, float* __restrict__ WThhl, float* __restrict__ WT1)
{
    const int b = blockIdx.x;
    const int t = threadIdx.x;

    if (b < 64) {                                    // transposes (81920 elements)
        for (int idx = b * 256 + t; idx < 81920; idx += 64 * 256) {
            int i = idx;
            if (i < 12288) { WTih[i] = W_ih[(i % 192) * 64 + i / 192]; continue; }
            i -= 12288;
            if (i < 12288) { WThh[i] = W_hh[(i % 192) * 64 + i / 192]; continue; }
            i -= 12288;
            if (i < 32768) { WTihl[i] = W_ihl[(i % 256) * 128 + i / 256]; continue; }
            i -= 32768;
            if (i < 16384) { WThhl[i] = W_hhl[(i % 256) * 64 + i / 256]; continue; }
            i -= 16384;
            WT1[i] = W1[(i % 64) * 128 + i / 64];
        }
        return;
    }
    if (b < 320) {                                   // lin0, 1024 waves grid-stride
        int wv = (b - 64) * 4 + (t >> 6);
        int lane = t & 63;
        float w0r[32];
#pragma unroll
        for (int f = 0; f < 32; ++f) w0r[f] = W0[lane * 32 + f];
        float b0v = b0[lane];
        for (int n = wv; n < NN; n += 1024) {
            float xv = (lane < 32) ? x[n * 32 + lane] : 0.f;
            float acc = b0v;
#pragma unroll
            for (int f = 0; f < 32; ++f) acc += __shfl(xv, f, 64) * w0r[f];
            float rv = fmaxf(acc, 0.f);
            h[n * 64 + lane] = rv;
            outb[n * 64 + lane] = f2bf(rv);
        }
        return;
    }
    if (b < 832) {                                   // edge MLP over NE*128
        for (int idx = (b - 320) * 256 + t; idx < NE * 128; idx += 512 * 256) {
            int e = idx >> 7, k = idx & 127;
            float acc = be1[k];
#pragma unroll
            for (int j = 0; j < 5; ++j)
                acc += ea[e * 5 + j] * We1[k * 5 + j];
            h1[idx] = f2bf(fmaxf(acc, 0.f));
        }
        return;
    }
    if (b < 960) {                                   // WtF: frag-major B for k_msg
        for (int idx = (b - 832) * 256 + t; idx < WTF_BIAS + 4096; idx += 128 * 256) {
            float v;
            if (idx < WTF_BIAS) {
                int j = idx & 7, lane = (idx >> 3) & 63;
                int nt = (idx >> 9) & 3, s4 = (idx >> 11) & 3, ch = idx >> 13;
                int o = nt * 16 + (lane & 15);
                int k = s4 * 32 + (lane >> 4) * 8 + j;
                v = We2[(size_t)(ch * 64 + o) * 128 + k];
            } else {
                int bx = idx - WTF_BIAS;
                int j = bx & 7, lane = (bx >> 3) & 63;
                int nt = (bx >> 9) & 3, sb = bx >> 11;
                int o = nt * 16 + (lane & 15);
                int i = sb * 32 + (lane >> 4) * 8 + j;
                v = be2[i * 64 + o];
            }
            WtF[idx] = f2bf(v);
        }
        return;
    }
    if (b < 992) {                                   // degree count
        for (int e = (b - 960) * 256 + t; e < NE; e += 32 * 256)
            atomicAdd(&cnt[ei[NE + e]], 1);
        return;
    }
    {                                                // graph ranges (batch sorted)
        for (int idx = (b - 992) * 256 + t; idx < NN; idx += 32 * 256) {
            int bg = batch[idx];
            if (idx == 0 || batch[idx - 1] != bg) gstart[bg] = idx;
            if (idx == NN - 1 || batch[idx + 1] != bg) gend[bg] = idx + 1;
        }
    }
}

// ---------------- exclusive prefix over cnt -> rowptr[NN+1], one block ----------
__global__ __launch_bounds__(1024) void k_scan(const int* __restrict__ cnt,
                                               int* __restrict__ rowptr)
{
    __shared__ int ps[1024];
    int t = threadIdx.x;
    int base = t * 20;
    int loc[20];
    int s = 0;
#pragma unroll
    for (int i = 0; i < 20; ++i) {
        int idx = base + i;
        loc[i] = s;
        s += (idx < NN) ? cnt[idx] : 0;
    }
    ps[t] = s;
    __syncthreads();
    for (int off = 1; off < 1024; off <<= 1) {
        int v = (t >= off) ? ps[t - off] : 0;
        __syncthreads();
        ps[t] += v;
        __syncthreads();
    }
    int ex = (t > 0) ? ps[t - 1] : 0;
#pragma unroll
    for (int i = 0; i < 20; ++i) {
        int idx = base + i;
        if (idx < NN) rowptr[idx] = ex + loc[i];
    }
    if (t == 1023) rowptr[NN] = ps[1023];
}

// ---------------- scatter edge ids into CSR ----------------
__global__ __launch_bounds__(256) void k_scatter(const int* __restrict__ ei,
    const int* __restrict__ rowptr, int* __restrict__ cur, int* __restrict__ eids)
{
    for (int e = blockIdx.x * 256 + threadIdx.x; e < NE; e += gridDim.x * 256) {
        int d = ei[NE + e];
        int pos = atomicAdd(&cur[d], 1);
        eids[rowptr[d] + pos] = e;
    }
}

// ---------------- message GEMM: pipelined frag-major B, barrier-free K-loop -----
// 256 edges/block = 4 waves; B-frag groups double-buffered in registers
// (prefetch s4+1 during s4's MFMA). sv stored TRANSPOSED (svT[ch][row]) so the
// per-chunk scale phase is 4x ds_read_b64 instead of 16x ds_read_u16.
__global__ __launch_bounds__(256, 2) void k_msg(
    const u16* __restrict__ outb, const u16* __restrict__ h1,
    const u16* __restrict__ WtF, const int* __restrict__ ei,
    u16* __restrict__ pbuf)
{
    __shared__ __align__(8) u16 svT[64 * 260];   // sv transposed, pad 260
    __shared__ int sdst[256];
    const int t = threadIdx.x;
    const int eb0 = blockIdx.x * 256;
    const int kh = blockIdx.y;                   // 0..KH-1

    {
        int e = eb0 + t;
        sdst[t] = (e < NE) ? ei[NE + e] : 0;
    }
#pragma unroll
    for (int r = 0; r < 8; ++r) {                // gather out[src] -> svT
        int cid = t + 256 * r;
        int row = cid >> 3, c8 = cid & 7;
        int e = eb0 + row;
        u16x8 v = {};
        if (e < NE) { int s = ei[e]; v = *(const u16x8*)(outb + (size_t)s * 64 + c8 * 8); }
#pragma unroll
        for (int j = 0; j < 8; ++j)
            svT[(c8 * 8 + j) * 260 + row] = v[j];
    }

    const int lane = t & 63, w = t >> 6, r16 = lane & 15, q = lane >> 4;
    const int w64 = w * 64;

    // static A-fragments: h1 rows, reused across all chunks
    u16x8 h1r[4][4];
#pragma unroll
    for (int sub = 0; sub < 4; ++sub) {
        int e = eb0 + w64 + sub * 16 + r16;
        if (e >= NE) e = NE - 1;                 // contribution zeroed via sv=0
        const u16* hp = h1 + (size_t)e * 128 + q * 8;
#pragma unroll
        for (int s4 = 0; s4 < 4; ++s4)
            h1r[sub][s4] = *(const u16x8*)(hp + s4 * 32);
    }

    f32x4 acc[4][4];
    f32x4 P[4][4];
    const f32x4 z4 = {0.f, 0.f, 0.f, 0.f};
#pragma unroll
    for (int sub = 0; sub < 4; ++sub)
#pragma unroll
        for (int nt = 0; nt < 4; ++nt) acc[sub][nt] = z4;

    U8 bA[4], bB[4];
    auto LD = [&](U8* dst, int ch, int s4) {
        const u16* p = WtF + (size_t)ch * 8192 + s4 * 2048 + lane * 8;
#pragma unroll
        for (int nt = 0; nt < 4; ++nt)
            dst[nt].u = *(const u16x8*)(p + nt * 512);
    };
    auto MF0 = [&](U8* bv, int s4) {             // first group: C = 0 (no P init)
#pragma unroll
        for (int sub = 0; sub < 4; ++sub) {
            U8 a; a.u = h1r[sub][s4];
#pragma unroll
            for (int nt = 0; nt < 4; ++nt)
                P[sub][nt] = __builtin_amdgcn_mfma_f32_16x16x32_bf16(
                    a.b, bv[nt].b, z4, 0, 0, 0);
        }
    };
    auto MF = [&](U8* bv, int s4) {
#pragma unroll
        for (int sub = 0; sub < 4; ++sub) {
            U8 a; a.u = h1r[sub][s4];
#pragma unroll
            for (int nt = 0; nt < 4; ++nt)
                P[sub][nt] = __builtin_amdgcn_mfma_f32_16x16x32_bf16(
                    a.b, bv[nt].b, P[sub][nt], 0, 0, 0);
        }
    };

    __syncthreads();                             // the ONLY barrier
    LD(bA, kh * 16, 0);

#pragma unroll 1
    for (int cc = 0; cc < 16; ++cc) {
        const int ch = kh * 16 + cc;
        LD(bB, ch, 1);  MF0(bA, 0);
        LD(bA, ch, 2);  MF (bB, 1);
        LD(bB, ch, 3);  MF (bA, 2);
        if (cc < 15) LD(bA, ch + 1, 0);
        MF(bB, 3);

        // scale by sv: one b64 read per sub (rows mb..mb+3 of chunk column ch)
#pragma unroll
        for (int sub = 0; sub < 4; ++sub) {
            int mb = w64 + sub * 16 + q * 4;
            uint2 rv = *(const uint2*)&svT[ch * 260 + mb];
            union { unsigned u; float f; } c0, c1, c2, c3;
            c0.u = rv.x << 16; c1.u = rv.x & 0xffff0000u;
            c2.u = rv.y << 16; c3.u = rv.y & 0xffff0000u;
#pragma unroll
            for (int nt = 0; nt < 4; ++nt) {
                acc[sub][nt][0] += c0.f * P[sub][nt][0];
                acc[sub][nt][1] += c1.f * P[sub][nt][1];
                acc[sub][nt][2] += c2.f * P[sub][nt][2];
                acc[sub][nt][3] += c3.f * P[sub][nt][3];
            }
        }
    }

    if (kh == KH - 1) {   // bias block: A = out[src] rows (from svT), B = be2 frags
        U8 bvb[2][4];
#pragma unroll
        for (int sb = 0; sb < 2; ++sb)
#pragma unroll
            for (int nt = 0; nt < 4; ++nt)
                bvb[sb][nt].u = *(const u16x8*)(WtF + WTF_BIAS + ((sb * 4 + nt) * 64 + lane) * 8);
#pragma unroll
        for (int sub = 0; sub < 4; ++sub) {
            int m = w64 + sub * 16 + r16;
#pragma unroll
            for (int sb = 0; sb < 2; ++sb) {
                U8 a;
#pragma unroll
                for (int j = 0; j < 8; ++j)
                    a.u[j] = svT[(sb * 32 + q * 8 + j) * 260 + m];
#pragma unroll
                for (int nt = 0; nt < 4; ++nt)
                    acc[sub][nt] = __builtin_amdgcn_mfma_f32_16x16x32_bf16(
                        a.b, bvb[sb][nt].b, acc[sub][nt], 0, 0, 0);
            }
        }
    }

    // bf16 stores: pbuf[e][kh][o]
#pragma unroll
    for (int sub = 0; sub < 4; ++sub) {
#pragma unroll
        for (int r = 0; r < 4; ++r) {
            int e = eb0 + w64 + sub * 16 + q * 4 + r;
            if (e >= NE) continue;
            u16* pp = pbuf + (size_t)e * (KH * 64) + kh * 64 + r16;
#pragma unroll
            for (int nt = 0; nt < 4; ++nt)
                pp[nt * 16] = f2bf(acc[sub][nt][r]);
        }
    }
}

// -------- GRU cell: CSR aggregation + deg-norm + gates, 16 nodes/wave -----------
__global__ __launch_bounds__(256) void k_gru(float* __restrict__ h, u16* __restrict__ outb,
    const u16* __restrict__ pbuf, const int* __restrict__ rowptr,
    const int* __restrict__ eids, const float* __restrict__ b_conv,
    const float* __restrict__ WTih, const float* __restrict__ WThh,
    const float* __restrict__ b_ih, const float* __restrict__ b_hh)
{
    int wid = (blockIdx.x * blockDim.x + threadIdx.x) >> 6;
    int lane = threadIdx.x & 63;
    int n0 = wid * 16;
    if (n0 >= NN) return;
    float bcv = b_conv[lane];
    float m[16], hv[16];
#pragma unroll
    for (int p = 0; p < 16; ++p) {
        int n = n0 + p;
        int rs = rowptr[n], re = rowptr[n + 1];
        float v = 0.f;
        for (int j = rs; j < re; ++j) {
            const u16* pb = pbuf + (size_t)eids[j] * (KH * 64);
            v += bf2f(pb[lane]) + bf2f(pb[64 + lane])
               + bf2f(pb[128 + lane]) + bf2f(pb[192 + lane]);
        }
        float invd = 1.f / fmaxf((float)(re - rs), 1.f);
        m[p] = fmaxf(v * invd + bcv, 0.f);
        hv[p] = h[n * 64 + lane];
    }
    float air[16] = {}, aiz[16] = {}, ain[16] = {};
    float ahr[16] = {}, ahz[16] = {}, ahn[16] = {};
#pragma unroll 2
    for (int i = 0; i < 64; ++i) {
        const float* wi = WTih + i * 192;
        const float* wh = WThh + i * 192;
        float wir = wi[lane], wiz = wi[64 + lane], win = wi[128 + lane];
        float whr = wh[lane], whz = wh[64 + lane], whn = wh[128 + lane];
#pragma unroll
        for (int p = 0; p < 16; ++p) {
            float mi = __shfl(m[p], i, 64);
            float hi = __shfl(hv[p], i, 64);
            air[p] += mi * wir; aiz[p] += mi * wiz; ain[p] += mi * win;
            ahr[p] += hi * whr; ahz[p] += hi * whz; ahn[p] += hi * whn;
        }
    }
    float bir = b_ih[lane], biz = b_ih[64 + lane], bin = b_ih[128 + lane];
    float bhr = b_hh[lane], bhz = b_hh[64 + lane], bhn = b_hh[128 + lane];
#pragma unroll
    for (int p = 0; p < 16; ++p) {
        float r = sigmoidf(air[p] + bir + ahr[p] + bhr);
        float z = sigmoidf(aiz[p] + biz + ahz[p] + bhz);
        float nng = tanhf(ain[p] + bin + r * (ahn[p] + bhn));
        float hnew = (1.f - z) * nng + z * hv[p];
        h[(n0 + p) * 64 + lane] = hnew;
        outb[(n0 + p) * 64 + lane] = f2bf(hnew);
    }
}

// -------- fused Set2Set: 1 graph per block, 3x(LSTM + attention) + readout ------
__global__ __launch_bounds__(256) void k_s2s(const float* __restrict__ h,
    const int* __restrict__ gstart, const int* __restrict__ gend,
    const float* __restrict__ WTihl, const float* __restrict__ WThhl,
    const float* __restrict__ b_ihl, const float* __restrict__ b_hhl,
    const float* __restrict__ WT1, const float* __restrict__ b1,
    const float* __restrict__ W2, const float* __restrict__ b2,
    float* __restrict__ outp)
{
    __shared__ float qs[128];        // q_star for this graph
    __shared__ float hlL[64], clL[64];
    __shared__ float gt[256];
    __shared__ float sm[4], sl[4], sr[4][64];
    const int g = blockIdx.x;
    const int t = threadIdx.x, w = t >> 6, lane = t & 63;
    const int s = gstart[g], e = gend[g];

    if (t < 128) qs[t] = 0.f;
    if (t < 64) { hlL[t] = 0.f; clL[t] = 0.f; }
    __syncthreads();

    for (int step = 0; step < 3; ++step) {
        // ---- LSTM gates: thread t computes gate output o = t ----
        float ga = b_ihl[t] + b_hhl[t];
#pragma unroll 4
        for (int j = 0; j < 128; ++j)
            ga += qs[j] * WTihl[j * 256 + t];
#pragma unroll 4
        for (int j = 0; j < 64; ++j)
            ga += hlL[j] * WThhl[j * 256 + t];
        gt[t] = ga;
        __syncthreads();
        if (t < 64) {
            float cv = sigmoidf(gt[64 + t]) * clL[t] + sigmoidf(gt[t]) * tanhf(gt[128 + t]);
            float hn = sigmoidf(gt[192 + t]) * tanhf(cv);
            clL[t] = cv; hlL[t] = hn; qs[t] = hn;
        }
        __syncthreads();
        // ---- attention: 4 waves stride nodes, online softmax ----
        float qv = hlL[lane];
        float M = -3.4e38f, l = 0.f, r = 0.f;
        for (int n = s + w; n < e; n += 4) {
            float hvv = h[n * 64 + lane];
            float p = hvv * qv;
#pragma unroll
            for (int off = 32; off > 0; off >>= 1) p += __shfl_xor(p, off, 64);
            if (p > M) {
                float sc = __expf(M - p);
                l = l * sc + 1.f;
                r = r * sc + hvv;
                M = p;
            } else {
                float pe = __expf(p - M);
                l += pe;
                r += pe * hvv;
            }
        }
        if (lane == 0) { sm[w] = M; sl[w] = l; }
        sr[w][lane] = r;
        __syncthreads();
        if (w == 0) {
            float Mg = fmaxf(fmaxf(sm[0], sm[1]), fmaxf(sm[2], sm[3]));
            float lg = 0.f, rg = 0.f;
#pragma unroll
            for (int wp = 0; wp < 4; ++wp) {
                float sc = __expf(sm[wp] - Mg);     // finite sentinels: no NaN
                lg += sl[wp] * sc;
                rg += sr[wp][lane] * sc;
            }
            float inv = (lg > 0.f) ? 1.f / lg : 0.f;
            qs[64 + lane] = rg * inv;
        }
        __syncthreads();
    }
    // ---- readout: 4 waves split j, LDS reduce ----
    float acc = 0.f;
#pragma unroll 4
    for (int j = w * 32; j < w * 32 + 32; ++j)
        acc += qs[j] * WT1[j * 64 + lane];
    sr[w][lane] = acc;
    __syncthreads();
    if (w == 0) {
        float y = sr[0][lane] + sr[1][lane] + sr[2][lane] + sr[3][lane] + b1[lane];
        float pr = fmaxf(y, 0.f) * W2[lane];
#pragma unroll
        for (int off = 32; off > 0; off >>= 1) pr += __shfl_xor(pr, off, 64);
        if (lane == 0) outp[g] = pr + b2[0];
    }
}

extern "C" void kernel_launch(void* const* d_in, const int* in_sizes, int n_in,
                              void* d_out, int out_size, void* d_ws, size_t ws_size,
                              hipStream_t stream)
{
    const float* x      = (const float*)d_in[0];
    const float* ea     = (const float*)d_in[1];
    const int*   ei     = (const int*)d_in[2];
    const int*   batch  = (const int*)d_in[3];
    const float* W0     = (const float*)d_in[4];
    const float* b0     = (const float*)d_in[5];
    const float* We1    = (const float*)d_in[6];
    const float* be1    = (const float*)d_in[7];
    const float* We2    = (const float*)d_in[8];
    const float* be2    = (const float*)d_in[9];
    const float* b_conv = (const float*)d_in[10];
    const float* W_ih   = (const float*)d_in[11];
    const float* W_hh   = (const float*)d_in[12];
    const float* b_ih   = (const float*)d_in[13];
    const float* b_hh   = (const float*)d_in[14];
    const float* W_ihl  = (const float*)d_in[15];
    const float* W_hhl  = (const float*)d_in[16];
    const float* b_ihl  = (const float*)d_in[17];
    const float* b_hhl  = (const float*)d_in[18];
    const float* W1     = (const float*)d_in[19];
    const float* b1     = (const float*)d_in[20];
    const float* W2     = (const float*)d_in[21];
    const float* b2     = (const float*)d_in[22];
    float* outp = (float*)d_out;

    char* ws = (char*)d_ws;
    size_t off = 0;
    auto alloc = [&](size_t bytes) -> char* {
        char* p = ws + off;
        off += (bytes + 255) & ~(size_t)255;
        return p;
    };
    u16*   h1     = (u16*)  alloc((size_t)NE * 128 * 2);       // 10.24 MB
    u16*   WtF    = (u16*)  alloc((WTF_BIAS + 4096) * 2);      // 1.06 MB
    u16*   outb   = (u16*)  alloc((size_t)NN * 64 * 2);        // 2.56 MB
    float* h      = (float*)alloc((size_t)NN * 64 * 4);        // 5.12 MB
    u16*   pbuf   = (u16*)  alloc((size_t)NE * KH * 64 * 2);   // 20.48 MB
    int*   rowptr = (int*)  alloc((NN + 1) * 4);
    int*   eids   = (int*)  alloc(NE * 4);
    int*   cnt    = (int*)  alloc(NN * 4);     // cnt..gend contiguous, one memset
    int*   cur    = (int*)  alloc(NN * 4);
    int*   gstart = (int*)  alloc(NGR * 4);
    int*   gend   = (int*)  alloc(NGR * 4);
    float* WTih   = (float*)alloc(12288 * 4);
    float* WThh   = (float*)alloc(12288 * 4);
    float* WTihl  = (float*)alloc(32768 * 4);
    float* WThhl  = (float*)alloc(16384 * 4);
    float* WT1    = (float*)alloc(8192 * 4);
    if (off > ws_size) return;   // ~40.5 MB needed

    size_t zspan = (size_t)((char*)(gend + NGR) - (char*)cnt);
    hipMemsetAsync(cnt, 0, zspan, stream);

    k_pre<<<1024, 256, 0, stream>>>(x, ea, ei, batch, W0, b0, We1, be1, We2, be2,
                                    W_ih, W_hh, W_ihl, W_hhl, W1,
                                    h, outb, h1, WtF, cnt, gstart, gend,
                                    WTih, WThh, WTihl, WThhl, WT1);
    k_scan<<<1, 1024, 0, stream>>>(cnt, rowptr);
    k_scatter<<<64, 256, 0, stream>>>(ei, rowptr, cur, eids);

    dim3 mgrid((NE + 255) / 256, KH, 1);
    for (int it = 0; it < 3; ++it) {
        k_msg<<<mgrid, 256, 0, stream>>>(outb, h1, WtF, ei, pbuf);
        k_gru<<<313, 256, 0, stream>>>(h, outb, pbuf, rowptr, eids, b_conv,
                                       WTih, WThh, b_ih, b_hh);
    }
    k_s2s<<<NGR, 256, 0, stream>>>(h, gstart, gend, WTihl, WThhl, b_ihl, b_hhl,
                                   WT1, b1, W2, b2, outp);
}

// Round 9
// 522.138 us; speedup vs baseline: 1.6124x; 1.1471x over previous
//
#include <hip/hip_runtime.h>

#define NN 20000
#define NE 40000
#define NGR 1000
#define KH 4                      // K-split for k_msg; pbuf stride = KH*64
#define WTF_BIAS 524288           // u16 offset of bias frags in WtF

typedef unsigned short u16;
typedef u16 u16x8 __attribute__((ext_vector_type(8)));
typedef __bf16 bf16x8 __attribute__((ext_vector_type(8)));
typedef float f32x4 __attribute__((ext_vector_type(4)));

union U8 { u16x8 u; bf16x8 b; };

__device__ __forceinline__ u16 f2bf(float f) {
    union { float f; unsigned u; } v; v.f = f;
    unsigned r = v.u + 0x7FFF + ((v.u >> 16) & 1);   // RNE
    return (u16)(r >> 16);
}
__device__ __forceinline__ float bf2f(u16 h) {
    union { unsigned u; float f; } v; v.u = ((unsigned)h) << 16;
    return v.f;
}
__device__ __forceinline__ float sigmoidf(float x) { return 1.f / (1.f + __expf(-x)); }

// ---------------- degree count ----------------
__global__ __launch_bounds__(256) void k_cnt(const int* __restrict__ ei, int* __restrict__ cnt)
{
    for (int e = blockIdx.x * 256 + threadIdx.x; e < NE; e += gridDim.x * 256)
        atomicAdd(&cnt[ei[NE + e]], 1);
}

// ---------------- exclusive prefix over cnt -> rowptr[NN+1], one block ----------
__global__ __launch_bounds__(1024) void k_scan(const int* __restrict__ cnt,
                                               int* __restrict__ rowptr)
{
    __shared__ int ps[1024];
    int t = threadIdx.x;
    int base = t * 20;
    int loc[20];
    int s = 0;
#pragma unroll
    for (int i = 0; i < 20; ++i) {
        int idx = base + i;
        loc[i] = s;
        s += (idx < NN) ? cnt[idx] : 0;
    }
    ps[t] = s;
    __syncthreads();
    for (int off = 1; off < 1024; off <<= 1) {
        int v = (t >= off) ? ps[t - off] : 0;
        __syncthreads();
        ps[t] += v;
        __syncthreads();
    }
    int ex = (t > 0) ? ps[t - 1] : 0;
#pragma unroll
    for (int i = 0; i < 20; ++i) {
        int idx = base + i;
        if (idx < NN) rowptr[idx] = ex + loc[i];
    }
    if (t == 1023) rowptr[NN] = ps[1023];
}

// -------- scatter: epos[e] = dst-sorted slot; srcs[slot] = src[e] --------------
__global__ __launch_bounds__(256) void k_scatter(const int* __restrict__ ei,
    const int* __restrict__ rowptr, int* __restrict__ cur,
    int* __restrict__ epos, int* __restrict__ srcs)
{
    for (int e = blockIdx.x * 256 + threadIdx.x; e < NE; e += gridDim.x * 256) {
        int d = ei[NE + e];
        int pos = rowptr[d] + atomicAdd(&cur[d], 1);
        epos[e] = pos;
        srcs[pos] = ei[e];
    }
}

// ============ fused one-time preamble, 992 blocks, role by blockIdx range ======
// [0,64) transposes | [64,320) lin0 | [320,832) edge_mlp(sorted) | [832,960) WtF
// [960,992) graph ranges
__global__ __launch_bounds__(256) void k_pre(
    const float* __restrict__ x, const float* __restrict__ ea,
    const int* __restrict__ batch, const int* __restrict__ epos,
    const float* __restrict__ W0, const float* __restrict__ b0,
    const float* __restrict__ We1, const float* __restrict__ be1,
    const float* __restrict__ We2, const float* __restrict__ be2,
    const float* __restrict__ W_ih, const float* __restrict__ W_hh,
    const float* __restrict__ W_ihl, const float* __restrict__ W_hhl,
    const float* __restrict__ W1,
    float* __restrict__ h, u16* __restrict__ outb, u16* __restrict__ h1,
    u16* __restrict__ WtF, int* __restrict__ gstart, int* __restrict__ gend,
    float* __restrict__ WTih, float* __restrict__ WThh,
    float* __restrict__ WTihl, float* __restrict__ WThhl, float* __restrict__ WT1)
{
    const int b = blockIdx.x;
    const int t = threadIdx.x;

    if (b < 64) {                                    // transposes (81920 elements)
        for (int idx = b * 256 + t; idx < 81920; idx += 64 * 256) {
            int i = idx;
            if (i < 12288) { WTih[i] = W_ih[(i % 192) * 64 + i / 192]; continue; }
            i -= 12288;
            if (i < 12288) { WThh[i] = W_hh[(i % 192) * 64 + i / 192]; continue; }
            i -= 12288;
            if (i < 32768) { WTihl[i] = W_ihl[(i % 256) * 128 + i / 256]; continue; }
            i -= 32768;
            if (i < 16384) { WThhl[i] = W_hhl[(i % 256) * 64 + i / 256]; continue; }
            i -= 16384;
            WT1[i] = W1[(i % 64) * 128 + i / 64];
        }
        return;
    }
    if (b < 320) {                                   // lin0, 1024 waves grid-stride
        int wv = (b - 64) * 4 + (t >> 6);
        int lane = t & 63;
        float w0r[32];
#pragma unroll
        for (int f = 0; f < 32; ++f) w0r[f] = W0[lane * 32 + f];
        float b0v = b0[lane];
        for (int n = wv; n < NN; n += 1024) {
            float xv = (lane < 32) ? x[n * 32 + lane] : 0.f;
            float acc = b0v;
#pragma unroll
            for (int f = 0; f < 32; ++f) acc += __shfl(xv, f, 64) * w0r[f];
            float rv = fmaxf(acc, 0.f);
            h[n * 64 + lane] = rv;
            outb[n * 64 + lane] = f2bf(rv);
        }
        return;
    }
    if (b < 832) {                                   // edge MLP -> dst-sorted h1
        for (int idx = (b - 320) * 256 + t; idx < NE * 128; idx += 512 * 256) {
            int e = idx >> 7, k = idx & 127;
            float acc = be1[k];
#pragma unroll
            for (int j = 0; j < 5; ++j)
                acc += ea[e * 5 + j] * We1[k * 5 + j];
            h1[(size_t)epos[e] * 128 + k] = f2bf(fmaxf(acc, 0.f));
        }
        return;
    }
    if (b < 960) {                                   // WtF: frag-major B for k_msg
        for (int idx = (b - 832) * 256 + t; idx < WTF_BIAS + 4096; idx += 128 * 256) {
            float v;
            if (idx < WTF_BIAS) {
                int j = idx & 7, lane = (idx >> 3) & 63;
                int nt = (idx >> 9) & 3, s4 = (idx >> 11) & 3, ch = idx >> 13;
                int o = nt * 16 + (lane & 15);
                int k = s4 * 32 + (lane >> 4) * 8 + j;
                v = We2[(size_t)(ch * 64 + o) * 128 + k];
            } else {
                int bx = idx - WTF_BIAS;
                int j = bx & 7, lane = (bx >> 3) & 63;
                int nt = (bx >> 9) & 3, sb = bx >> 11;
                int o = nt * 16 + (lane & 15);
                int i = sb * 32 + (lane >> 4) * 8 + j;
                v = be2[i * 64 + o];
            }
            WtF[idx] = f2bf(v);
        }
        return;
    }
    {                                                // graph ranges (batch sorted)
        for (int idx = (b - 960) * 256 + t; idx < NN; idx += 32 * 256) {
            int bg = batch[idx];
            if (idx == 0 || batch[idx - 1] != bg) gstart[bg] = idx;
            if (idx == NN - 1 || batch[idx + 1] != bg) gend[bg] = idx + 1;
        }
    }
}

// ---------------- message GEMM: pipelined frag-major B, barrier-free K-loop -----
// Edge slots are dst-sorted; slot i's source node = srcs[i]. pbuf stores by slot.
__global__ __launch_bounds__(256, 2) void k_msg(
    const u16* __restrict__ outb, const u16* __restrict__ h1,
    const u16* __restrict__ WtF, const int* __restrict__ srcs,
    u16* __restrict__ pbuf)
{
    __shared__ __align__(8) u16 svT[64 * 260];   // sv transposed, pad 260
    const int t = threadIdx.x;
    const int eb0 = blockIdx.x * 256;
    const int kh = blockIdx.y;                   // 0..KH-1

#pragma unroll
    for (int r = 0; r < 8; ++r) {                // gather out[srcs] -> svT
        int cid = t + 256 * r;
        int row = cid >> 3, c8 = cid & 7;
        int e = eb0 + row;
        u16x8 v = {};
        if (e < NE) { int s = srcs[e]; v = *(const u16x8*)(outb + (size_t)s * 64 + c8 * 8); }
#pragma unroll
        for (int j = 0; j < 8; ++j)
            svT[(c8 * 8 + j) * 260 + row] = v[j];
    }

    const int lane = t & 63, w = t >> 6, r16 = lane & 15, q = lane >> 4;
    const int w64 = w * 64;

    // static A-fragments: h1 rows, reused across all chunks
    u16x8 h1r[4][4];
#pragma unroll
    for (int sub = 0; sub < 4; ++sub) {
        int e = eb0 + w64 + sub * 16 + r16;
        if (e >= NE) e = NE - 1;                 // contribution zeroed via sv=0
        const u16* hp = h1 + (size_t)e * 128 + q * 8;
#pragma unroll
        for (int s4 = 0; s4 < 4; ++s4)
            h1r[sub][s4] = *(const u16x8*)(hp + s4 * 32);
    }

    f32x4 acc[4][4];
    f32x4 P[4][4];
    const f32x4 z4 = {0.f, 0.f, 0.f, 0.f};
#pragma unroll
    for (int sub = 0; sub < 4; ++sub)
#pragma unroll
        for (int nt = 0; nt < 4; ++nt) acc[sub][nt] = z4;

    U8 bA[4], bB[4];
    auto LD = [&](U8* dst, int ch, int s4) {
        const u16* p = WtF + (size_t)ch * 8192 + s4 * 2048 + lane * 8;
#pragma unroll
        for (int nt = 0; nt < 4; ++nt)
            dst[nt].u = *(const u16x8*)(p + nt * 512);
    };
    auto MF0 = [&](U8* bv, int s4) {
#pragma unroll
        for (int sub = 0; sub < 4; ++sub) {
            U8 a; a.u = h1r[sub][s4];
#pragma unroll
            for (int nt = 0; nt < 4; ++nt)
                P[sub][nt] = __builtin_amdgcn_mfma_f32_16x16x32_bf16(
                    a.b, bv[nt].b, z4, 0, 0, 0);
        }
    };
    auto MF = [&](U8* bv, int s4) {
#pragma unroll
        for (int sub = 0; sub < 4; ++sub) {
            U8 a; a.u = h1r[sub][s4];
#pragma unroll
            for (int nt = 0; nt < 4; ++nt)
                P[sub][nt] = __builtin_amdgcn_mfma_f32_16x16x32_bf16(
                    a.b, bv[nt].b, P[sub][nt], 0, 0, 0);
        }
    };

    __syncthreads();                             // the ONLY barrier
    LD(bA, kh * 16, 0);

#pragma unroll 1
    for (int cc = 0; cc < 16; ++cc) {
        const int ch = kh * 16 + cc;
        LD(bB, ch, 1);  MF0(bA, 0);
        LD(bA, ch, 2);  MF (bB, 1);
        LD(bB, ch, 3);  MF (bA, 2);
        if (cc < 15) LD(bA, ch + 1, 0);
        MF(bB, 3);

        // scale by sv: one b64 read per sub
#pragma unroll
        for (int sub = 0; sub < 4; ++sub) {
            int mb = w64 + sub * 16 + q * 4;
            uint2 rv = *(const uint2*)&svT[ch * 260 + mb];
            union { unsigned u; float f; } c0, c1, c2, c3;
            c0.u = rv.x << 16; c1.u = rv.x & 0xffff0000u;
            c2.u = rv.y << 16; c3.u = rv.y & 0xffff0000u;
#pragma unroll
            for (int nt = 0; nt < 4; ++nt) {
                acc[sub][nt][0] += c0.f * P[sub][nt][0];
                acc[sub][nt][1] += c1.f * P[sub][nt][1];
                acc[sub][nt][2] += c2.f * P[sub][nt][2];
                acc[sub][nt][3] += c3.f * P[sub][nt][3];
            }
        }
    }

    if (kh == KH - 1) {   // bias block: A = out[src] rows (from svT), B = be2 frags
        U8 bvb[2][4];
#pragma unroll
        for (int sb = 0; sb < 2; ++sb)
#pragma unroll
            for (int nt = 0; nt < 4; ++nt)
                bvb[sb][nt].u = *(const u16x8*)(WtF + WTF_BIAS + ((sb * 4 + nt) * 64 + lane) * 8);
#pragma unroll
        for (int sub = 0; sub < 4; ++sub) {
            int m = w64 + sub * 16 + r16;
#pragma unroll
            for (int sb = 0; sb < 2; ++sb) {
                U8 a;
#pragma unroll
                for (int j = 0; j < 8; ++j)
                    a.u[j] = svT[(sb * 32 + q * 8 + j) * 260 + m];
#pragma unroll
                for (int nt = 0; nt < 4; ++nt)
                    acc[sub][nt] = __builtin_amdgcn_mfma_f32_16x16x32_bf16(
                        a.b, bvb[sb][nt].b, acc[sub][nt], 0, 0, 0);
            }
        }
    }

    // bf16 stores: pbuf[slot][kh][o]
#pragma unroll
    for (int sub = 0; sub < 4; ++sub) {
#pragma unroll
        for (int r = 0; r < 4; ++r) {
            int e = eb0 + w64 + sub * 16 + q * 4 + r;
            if (e >= NE) continue;
            u16* pp = pbuf + (size_t)e * (KH * 64) + kh * 64 + r16;
#pragma unroll
            for (int nt = 0; nt < 4; ++nt)
                pp[nt * 16] = f2bf(acc[sub][nt][r]);
        }
    }
}

// -------- GRU cell: STREAMING CSR aggregation + gates, 8 nodes/wave -------------
__global__ __launch_bounds__(256) void k_gru(float* __restrict__ h, u16* __restrict__ outb,
    const u16* __restrict__ pbuf, const int* __restrict__ rowptr,
    const float* __restrict__ b_conv,
    const float* __restrict__ WTih, const float* __restrict__ WThh,
    const float* __restrict__ b_ih, const float* __restrict__ b_hh)
{
    int wid = (blockIdx.x * blockDim.x + threadIdx.x) >> 6;
    int lane = threadIdx.x & 63;
    int n0 = wid * 8;
    if (n0 >= NN) return;
    float bcv = b_conv[lane];
    float m[8], hv[8];
    int rs = rowptr[n0];
#pragma unroll
    for (int p = 0; p < 8; ++p) {
        int n = n0 + p;
        int re = rowptr[n + 1];
        float v = 0.f;
        const u16* pb = pbuf + (size_t)rs * (KH * 64);
        for (int j = rs; j < re; ++j) {          // contiguous 512B rows
            v += bf2f(pb[lane]) + bf2f(pb[64 + lane])
               + bf2f(pb[128 + lane]) + bf2f(pb[192 + lane]);
            pb += KH * 64;
        }
        float invd = 1.f / fmaxf((float)(re - rs), 1.f);
        m[p] = fmaxf(v * invd + bcv, 0.f);
        hv[p] = h[n * 64 + lane];
        rs = re;
    }
    float air[8] = {}, aiz[8] = {}, ain[8] = {};
    float ahr[8] = {}, ahz[8] = {}, ahn[8] = {};
#pragma unroll 4
    for (int i = 0; i < 64; ++i) {
        const float* wi = WTih + i * 192;
        const float* wh = WThh + i * 192;
        float wir = wi[lane], wiz = wi[64 + lane], win = wi[128 + lane];
        float whr = wh[lane], whz = wh[64 + lane], whn = wh[128 + lane];
#pragma unroll
        for (int p = 0; p < 8; ++p) {
            float mi = __shfl(m[p], i, 64);
            float hi = __shfl(hv[p], i, 64);
            air[p] += mi * wir; aiz[p] += mi * wiz; ain[p] += mi * win;
            ahr[p] += hi * whr; ahz[p] += hi * whz; ahn[p] += hi * whn;
        }
    }
    float bir = b_ih[lane], biz = b_ih[64 + lane], bin = b_ih[128 + lane];
    float bhr = b_hh[lane], bhz = b_hh[64 + lane], bhn = b_hh[128 + lane];
#pragma unroll
    for (int p = 0; p < 8; ++p) {
        float r = sigmoidf(air[p] + bir + ahr[p] + bhr);
        float z = sigmoidf(aiz[p] + biz + ahz[p] + bhz);
        float nng = tanhf(ain[p] + bin + r * (ahn[p] + bhn));
        float hnew = (1.f - z) * nng + z * hv[p];
        h[(n0 + p) * 64 + lane] = hnew;
        outb[(n0 + p) * 64 + lane] = f2bf(hnew);
    }
}

// -------- fused Set2Set: 1 graph per block, 3x(LSTM + attention) + readout ------
__global__ __launch_bounds__(256) void k_s2s(const float* __restrict__ h,
    const int* __restrict__ gstart, const int* __restrict__ gend,
    const float* __restrict__ WTihl, const float* __restrict__ WThhl,
    const float* __restrict__ b_ihl, const float* __restrict__ b_hhl,
    const float* __restrict__ WT1, const float* __restrict__ b1,
    const float* __restrict__ W2, const float* __restrict__ b2,
    float* __restrict__ outp)
{
    __shared__ float qs[128];        // q_star for this graph
    __shared__ float hlL[64], clL[64];
    __shared__ float gt[256];
    __shared__ float sm[4], sl[4], sr[4][64];
    const int g = blockIdx.x;
    const int t = threadIdx.x, w = t >> 6, lane = t & 63;
    const int s = gstart[g], e = gend[g];

    if (t < 128) qs[t] = 0.f;
    if (t < 64) { hlL[t] = 0.f; clL[t] = 0.f; }
    __syncthreads();

    for (int step = 0; step < 3; ++step) {
        float ga = b_ihl[t] + b_hhl[t];
#pragma unroll 4
        for (int j = 0; j < 128; ++j)
            ga += qs[j] * WTihl[j * 256 + t];
#pragma unroll 4
        for (int j = 0; j < 64; ++j)
            ga += hlL[j] * WThhl[j * 256 + t];
        gt[t] = ga;
        __syncthreads();
        if (t < 64) {
            float cv = sigmoidf(gt[64 + t]) * clL[t] + sigmoidf(gt[t]) * tanhf(gt[128 + t]);
            float hn = sigmoidf(gt[192 + t]) * tanhf(cv);
            clL[t] = cv; hlL[t] = hn; qs[t] = hn;
        }
        __syncthreads();
        float qv = hlL[lane];
        float M = -3.4e38f, l = 0.f, r = 0.f;
        for (int n = s + w; n < e; n += 4) {
            float hvv = h[n * 64 + lane];
            float p = hvv * qv;
#pragma unroll
            for (int off = 32; off > 0; off >>= 1) p += __shfl_xor(p, off, 64);
            if (p > M) {
                float sc = __expf(M - p);
                l = l * sc + 1.f;
                r = r * sc + hvv;
                M = p;
            } else {
                float pe = __expf(p - M);
                l += pe;
                r += pe * hvv;
            }
        }
        if (lane == 0) { sm[w] = M; sl[w] = l; }
        sr[w][lane] = r;
        __syncthreads();
        if (w == 0) {
            float Mg = fmaxf(fmaxf(sm[0], sm[1]), fmaxf(sm[2], sm[3]));
            float lg = 0.f, rg = 0.f;
#pragma unroll
            for (int wp = 0; wp < 4; ++wp) {
                float sc = __expf(sm[wp] - Mg);
                lg += sl[wp] * sc;
                rg += sr[wp][lane] * sc;
            }
            float inv = (lg > 0.f) ? 1.f / lg : 0.f;
            qs[64 + lane] = rg * inv;
        }
        __syncthreads();
    }
    float acc = 0.f;
#pragma unroll 4
    for (int j = w * 32; j < w * 32 + 32; ++j)
        acc += qs[j] * WT1[j * 64 + lane];
    sr[w][lane] = acc;
    __syncthreads();
    if (w == 0) {
        float y = sr[0][lane] + sr[1][lane] + sr[2][lane] + sr[3][lane] + b1[lane];
        float pr = fmaxf(y, 0.f) * W2[lane];
#pragma unroll
        for (int off = 32; off > 0; off >>= 1) pr += __shfl_xor(pr, off, 64);
        if (lane == 0) outp[g] = pr + b2[0];
    }
}

extern "C" void kernel_launch(void* const* d_in, const int* in_sizes, int n_in,
                              void* d_out, int out_size, void* d_ws, size_t ws_size,
                              hipStream_t stream)
{
    const float* x      = (const float*)d_in[0];
    const float* ea     = (const float*)d_in[1];
    const int*   ei     = (const int*)d_in[2];
    const int*   batch  = (const int*)d_in[3];
    const float* W0     = (const float*)d_in[4];
    const float* b0     = (const float*)d_in[5];
    const float* We1    = (const float*)d_in[6];
    const float* be1    = (const float*)d_in[7];
    const float* We2    = (const float*)d_in[8];
    const float* be2    = (const float*)d_in[9];
    const float* b_conv = (const float*)d_in[10];
    const float* W_ih   = (const float*)d_in[11];
    const float* W_hh   = (const float*)d_in[12];
    const float* b_ih   = (const float*)d_in[13];
    const float* b_hh   = (const float*)d_in[14];
    const float* W_ihl  = (const float*)d_in[15];
    const float* W_hhl  = (const float*)d_in[16];
    const float* b_ihl  = (const float*)d_in[17];
    const float* b_hhl  = (const float*)d_in[18];
    const float* W1     = (const float*)d_in[19];
    const float* b1     = (const float*)d_in[20];
    const float* W2     = (const float*)d_in[21];
    const float* b2     = (const float*)d_in[22];
    float* outp = (float*)d_out;

    char* ws = (char*)d_ws;
    size_t off = 0;
    auto alloc = [&](size_t bytes) -> char* {
        char* p = ws + off;
        off += (bytes + 255) & ~(size_t)255;
        return p;
    };
    u16*   h1     = (u16*)  alloc((size_t)NE * 128 * 2);       // 10.24 MB (sorted)
    u16*   WtF    = (u16*)  alloc((WTF_BIAS + 4096) * 2);      // 1.06 MB
    u16*   outb   = (u16*)  alloc((size_t)NN * 64 * 2);        // 2.56 MB
    float* h      = (float*)alloc((size_t)NN * 64 * 4);        // 5.12 MB
    u16*   pbuf   = (u16*)  alloc((size_t)NE * KH * 64 * 2);   // 20.48 MB (sorted)
    int*   rowptr = (int*)  alloc((NN + 1) * 4);
    int*   epos   = (int*)  alloc(NE * 4);
    int*   srcs   = (int*)  alloc(NE * 4);
    int*   cnt    = (int*)  alloc(NN * 4);     // cnt..gend contiguous, one memset
    int*   cur    = (int*)  alloc(NN * 4);
    int*   gstart = (int*)  alloc(NGR * 4);
    int*   gend   = (int*)  alloc(NGR * 4);
    float* WTih   = (float*)alloc(12288 * 4);
    float* WThh   = (float*)alloc(12288 * 4);
    float* WTihl  = (float*)alloc(32768 * 4);
    float* WThhl  = (float*)alloc(16384 * 4);
    float* WT1    = (float*)alloc(8192 * 4);
    if (off > ws_size) return;   // ~41 MB needed

    size_t zspan = (size_t)((char*)(gend + NGR) - (char*)cnt);
    hipMemsetAsync(cnt, 0, zspan, stream);

    k_cnt<<<64, 256, 0, stream>>>(ei, cnt);
    k_scan<<<1, 1024, 0, stream>>>(cnt, rowptr);
    k_scatter<<<64, 256, 0, stream>>>(ei, rowptr, cur, epos, srcs);
    k_pre<<<992, 256, 0, stream>>>(x, ea, batch, epos, W0, b0, We1, be1, We2, be2,
                                   W_ih, W_hh, W_ihl, W_hhl, W1,
                                   h, outb, h1, WtF, gstart, gend,
                                   WTih, WThh, WTihl, WThhl, WT1);

    dim3 mgrid((NE + 255) / 256, KH, 1);
    for (int it = 0; it < 3; ++it) {
        k_msg<<<mgrid, 256, 0, stream>>>(outb, h1, WtF, srcs, pbuf);
        k_gru<<<625, 256, 0, stream>>>(h, outb, pbuf, rowptr, b_conv,
                                       WTih, WThh, b_ih, b_hh);
    }
    k_s2s<<<NGR, 256, 0, stream>>>(h, gstart, gend, WTihl, WThhl, b_ihl, b_hhl,
                                   WT1, b1, W2, b2, outp);
}